// Round 13
// baseline (175.820 us; speedup 1.0000x reference)
//
#include <hip/hip_runtime.h>

#define T_SEQ   2048
#define DM      2048
#define N_Q     16
#define N_KV    4
#define HD      128
#define WIN     512
#define NB      2
#define NQKV    3072
// 1/sqrt(128) * log2(e): attention computed in exp2 domain
#define QK_SCALE_L2E 0.12751744f

typedef short bf16x8 __attribute__((ext_vector_type(8)));
typedef float f32x4  __attribute__((ext_vector_type(4)));
typedef float f32x16 __attribute__((ext_vector_type(16)));
typedef unsigned short us4v __attribute__((ext_vector_type(4)));

__device__ __forceinline__ unsigned short f2bf(float f) {
    union { float f; unsigned u; } v; v.f = f;
    unsigned u = v.u;
    u += 0x7fffu + ((u >> 16) & 1u);           // RNE
    return (unsigned short)(u >> 16);
}
__device__ __forceinline__ float bf2f(unsigned short h) {
    union { unsigned u; float f; } v; v.u = ((unsigned)h) << 16;
    return v.f;
}
__device__ __forceinline__ unsigned cvt_pk_bf16(float a, float b) {
    unsigned r;
    asm("v_cvt_pk_bf16_f32 %0, %1, %2" : "=v"(r) : "v"(a), "v"(b));
    return r;   // low16 = bf16(a), high16 = bf16(b)
}

#define GLOAD_LDS16(g, l) __builtin_amdgcn_global_load_lds( \
    (const __attribute__((address_space(1))) void*)(g),     \
    (__attribute__((address_space(3))) void*)(l), 16, 0, 0)

struct us4 { unsigned short a, b, c, d; };

// ---------------- fused prep A: x->bf16, 4 weight transposes, rope table ----------------
// flat grid: [0,8192) x-convert | [8192,18432) transposes | [18432,18944) rope table

__global__ __launch_bounds__(256)
void prep_a(const float* __restrict__ x, const float* __restrict__ wq,
            const float* __restrict__ wk, const float* __restrict__ wv,
            const float* __restrict__ wo,
            unsigned short* __restrict__ xbf, unsigned short* __restrict__ wqkvT,
            unsigned short* __restrict__ woT,
            float* __restrict__ cosT, float* __restrict__ sinT) {
    __shared__ float tile[32][33];
    int blk = blockIdx.x;
    if (blk < 8192) {                               // x: f32 -> bf16, 4 elems/thread
        long i = ((long)blk * 256 + threadIdx.x) * 4;
        float4 f = *(const float4*)(x + i);
        us4 o; o.a = f2bf(f.x); o.b = f2bf(f.y); o.c = f2bf(f.z); o.d = f2bf(f.w);
        *(us4*)(xbf + i) = o;
        return;
    }
    blk -= 8192;
    if (blk < 10240) {                              // weight transposes
        const float* in; unsigned short* outp; int C, bx, by;
        if (blk < 4096)      { in = wq; outp = wqkvT;                         C = DM;  bx = blk & 63;          by = blk >> 6; }
        else if (blk < 5120) { int k = blk - 4096; in = wk; outp = wqkvT + (long)DM * DM;         C = 512; bx = k & 15; by = k >> 4; }
        else if (blk < 6144) { int k = blk - 5120; in = wv; outp = wqkvT + (long)(DM + 512) * DM; C = 512; bx = k & 15; by = k >> 4; }
        else                 { int k = blk - 6144; in = wo; outp = woT;                           C = DM;  bx = k & 63; by = k >> 6; }
        const int c0 = bx * 32, r0 = by * 32;
        const int tx = threadIdx.x & 31, ty = threadIdx.x >> 5;
#pragma unroll
        for (int i = 0; i < 4; ++i)
            tile[ty + i * 8][tx] = in[(long)(r0 + ty + i * 8) * C + c0 + tx];
        __syncthreads();
#pragma unroll
        for (int i = 0; i < 4; ++i)
            outp[(long)(c0 + ty + i * 8) * DM + r0 + tx] = f2bf(tile[tx][ty + i * 8]);
        return;
    }
    blk -= 10240;                                   // rope table (512 blocks)
    const int idx = blk * 256 + threadIdx.x;        // < 2048*64
    const int t = idx >> 6, d = idx & 63;
    const float inv = __expf(-(float)d * (9.210340371976184f / 64.0f)); // 10000^(-d/64)
    const float ang = (float)t * inv;
    cosT[idx] = cosf(ang);
    sinT[idx] = sinf(ang);
}

// ---------------- prep B: v transpose only (rope is fused into gemm_qkv) ----------------
// qkv v-cols [2560,3072) -> vt[b][hkv][d][t]; 2048 blocks

__global__ __launch_bounds__(256)
void prep_b(const unsigned short* __restrict__ qkv, unsigned short* __restrict__ vt) {
    __shared__ unsigned short stile[32][33];
    const int blk = blockIdx.x;
    const int bh = blk >> 8;                        // b*4 + hkv
    const int d0 = ((blk >> 6) & 3) * 32;
    const int t0 = (blk & 63) * 32;
    const int tx = threadIdx.x & 31, ty = threadIdx.x >> 5;
    const long inbase = (long)(bh >> 2) * T_SEQ;
    const int coff = DM + N_KV * HD + (bh & 3) * HD;   // 2560 + hkv*128
#pragma unroll
    for (int i = 0; i < 4; ++i)
        stile[ty + i * 8][tx] = qkv[(inbase + t0 + ty + i * 8) * NQKV + coff + d0 + tx];
    __syncthreads();
#pragma unroll
    for (int i = 0; i < 4; ++i)
        vt[((long)bh * HD + d0 + ty + i * 8) * T_SEQ + t0 + tx] = stile[tx][ty + i * 8];
}

// ---------------- qkv GEMM with fused RoPE epilogue ----------------
// m97 structure, 32x32x16 MFMA. Wave columns remapped to two 32-wide strips
// at distance 64 (wcs + tj*64) so the RoPE pair (d, d+64) sits in the SAME
// thread: acc[ti][0] and acc[ti][1]. q/k col-blocks (hb<20) rotate in
// registers (full f32, better than the old bf16-roundtrip rope) and scale q
// by log2e/sqrt(hd); v col-blocks write plain bf16.

__global__ __launch_bounds__(256)
void gemm_qkv(const unsigned short* __restrict__ A,
              const unsigned short* __restrict__ Bt,
              unsigned short* __restrict__ C,
              const float* __restrict__ cosT, const float* __restrict__ sinT) {
    const int K = DM, ldc = NQKV;
    __shared__ __align__(16) unsigned short sA[128 * 64];
    __shared__ __align__(16) unsigned short sB[128 * 64];
    const int tid = threadIdx.x;
    const int lane = tid & 63;
    const int wid = tid >> 6;
    const int wr  = (wid >> 1) * 64;
    const int wcs = (wid & 1) * 32;            // col strips [wcs,wcs+32) and +64
    const int l5 = lane >> 5, l31 = lane & 31;

    // XCD-aware bijective swizzle (nwg = 768, divisible by 8)
    const int gx = gridDim.x;
    const int nwg = gx * gridDim.y;
    int flat = blockIdx.y * gx + blockIdx.x;
    flat = (flat & 7) * (nwg >> 3) + (flat >> 3);
    const long Arow0 = (long)(flat / gx) * 128;
    const long Brow0 = (long)(flat % gx) * 128;

    f32x16 acc[2][2] = {};

    for (int kt = 0; kt < K; kt += 64) {
        __syncthreads();
#pragma unroll
        for (int n = 0; n < 4; ++n) {
            const int linb = n * 256 + wid * 64;      // wave-uniform 16B-chunk base
            const int lin  = linb + lane;             // this lane's chunk
            const int row  = lin >> 3;                // 8 chunks per 64-elem row
            const int sw   = (row ^ (row >> 3)) & 7;
            const int sc   = (lin & 7) ^ sw;          // pre-swizzled global source
            const unsigned short* gA = A  + (Arow0 + row) * K + kt + sc * 8;
            const unsigned short* gB = Bt + (Brow0 + row) * K + kt + sc * 8;
            GLOAD_LDS16(gA, &sA[linb * 8]);
            GLOAD_LDS16(gB, &sB[linb * 8]);
        }
        __syncthreads();
#pragma unroll
        for (int kc = 0; kc < 4; ++kc) {
            bf16x8 av[2], bv[2];
#pragma unroll
            for (int t = 0; t < 2; ++t) {
                const int rowa = wr + t * 32 + l31;
                const int ca = (kc * 2 + l5) ^ ((rowa ^ (rowa >> 3)) & 7);
                av[t] = *(const bf16x8*)&sA[rowa * 64 + ca * 8];
                const int rowb = wcs + t * 64 + l31;
                const int cb = (kc * 2 + l5) ^ ((rowb ^ (rowb >> 3)) & 7);
                bv[t] = *(const bf16x8*)&sB[rowb * 64 + cb * 8];
            }
#pragma unroll
            for (int ti = 0; ti < 2; ++ti)
#pragma unroll
                for (int tj = 0; tj < 2; ++tj)
                    acc[ti][tj] = __builtin_amdgcn_mfma_f32_32x32x16_bf16(av[ti], bv[tj], acc[ti][tj], 0, 0, 0);
        }
    }

    // C/D map (m74/m101): col = lane&31, row = (r&3) + 8*(r>>2) + 4*(lane>>5)
    const int hb = (int)(Brow0 >> 7);               // 0..23: 0-15 q, 16-19 k, 20-23 v
    if (hb < 20) {
        const float sc = (hb < 16) ? QK_SCALE_L2E : 1.0f;
        const int d6 = wcs + l31;                   // [0,64)
        const long colL = Brow0 + d6;
#pragma unroll
        for (int ti = 0; ti < 2; ++ti)
#pragma unroll
            for (int r = 0; r < 16; ++r) {
                const long row = Arow0 + wr + ti * 32 + (r & 3) + 8 * (r >> 2) + 4 * l5;
                const int t = (int)(row & (T_SEQ - 1));
                const float c = cosT[t * 64 + d6];
                const float s = sinT[t * 64 + d6];
                const float a = acc[ti][0][r], b = acc[ti][1][r];
                C[row * ldc + colL]      = f2bf((a * c - b * s) * sc);
                C[row * ldc + colL + 64] = f2bf((b * c + a * s) * sc);
            }
    } else {
#pragma unroll
        for (int ti = 0; ti < 2; ++ti)
#pragma unroll
            for (int tj = 0; tj < 2; ++tj)
#pragma unroll
                for (int r = 0; r < 16; ++r) {
                    const long row = Arow0 + wr + ti * 32 + (r & 3) + 8 * (r >> 2) + 4 * l5;
                    const long col = Brow0 + wcs + tj * 64 + l31;
                    C[row * ldc + col] = f2bf(acc[ti][tj][r]);
                }
    }
}

// ---------------- GEMM: C[M][ldc] = A[M][K] * Bt[N][K]^T  (wo projection) ----------------
// m97 structure, 32x32x16 MFMA, fp32 output.

__global__ __launch_bounds__(256)
void gemm_bt(const unsigned short* __restrict__ A,
             const unsigned short* __restrict__ Bt,
             float* __restrict__ C, int K, int ldc) {
    __shared__ __align__(16) unsigned short sA[128 * 64];
    __shared__ __align__(16) unsigned short sB[128 * 64];
    const int tid = threadIdx.x;
    const int lane = tid & 63;
    const int wid = tid >> 6;
    const int wr = (wid >> 1) * 64, wc = (wid & 1) * 64;
    const int l5 = lane >> 5, l31 = lane & 31;

    // XCD-aware bijective swizzle (nwg divisible by 8 in all launches)
    const int gx = gridDim.x;
    const int nwg = gx * gridDim.y;
    int flat = blockIdx.y * gx + blockIdx.x;
    flat = (flat & 7) * (nwg >> 3) + (flat >> 3);
    const long Arow0 = (long)(flat / gx) * 128;
    const long Brow0 = (long)(flat % gx) * 128;

    f32x16 acc[2][2] = {};

    for (int kt = 0; kt < K; kt += 64) {
        __syncthreads();
#pragma unroll
        for (int n = 0; n < 4; ++n) {
            const int linb = n * 256 + wid * 64;      // wave-uniform 16B-chunk base
            const int lin  = linb + lane;             // this lane's chunk
            const int row  = lin >> 3;                // 8 chunks per 64-elem row
            const int sw   = (row ^ (row >> 3)) & 7;
            const int sc   = (lin & 7) ^ sw;          // pre-swizzled global source
            const unsigned short* gA = A  + (Arow0 + row) * K + kt + sc * 8;
            const unsigned short* gB = Bt + (Brow0 + row) * K + kt + sc * 8;
            GLOAD_LDS16(gA, &sA[linb * 8]);
            GLOAD_LDS16(gB, &sB[linb * 8]);
        }
        __syncthreads();
#pragma unroll
        for (int kc = 0; kc < 4; ++kc) {
            bf16x8 av[2], bv[2];
#pragma unroll
            for (int t = 0; t < 2; ++t) {
                const int rowa = wr + t * 32 + l31;
                const int ca = (kc * 2 + l5) ^ ((rowa ^ (rowa >> 3)) & 7);
                av[t] = *(const bf16x8*)&sA[rowa * 64 + ca * 8];
                const int rowb = wc + t * 32 + l31;
                const int cb = (kc * 2 + l5) ^ ((rowb ^ (rowb >> 3)) & 7);
                bv[t] = *(const bf16x8*)&sB[rowb * 64 + cb * 8];
            }
#pragma unroll
            for (int ti = 0; ti < 2; ++ti)
#pragma unroll
                for (int tj = 0; tj < 2; ++tj)
                    acc[ti][tj] = __builtin_amdgcn_mfma_f32_32x32x16_bf16(av[ti], bv[tj], acc[ti][tj], 0, 0, 0);
        }
    }

#pragma unroll
    for (int ti = 0; ti < 2; ++ti)
#pragma unroll
        for (int tj = 0; tj < 2; ++tj)
#pragma unroll
            for (int r = 0; r < 16; ++r) {
                const long row = Arow0 + wr + ti * 32 + (r & 3) + 8 * (r >> 2) + 4 * l5;
                const long col = Brow0 + wc + tj * 32 + l31;
                C[row * ldc + col] = acc[ti][tj][r];
            }
}

// ---------------- flash attention, sliding window ----------------
// grid (T/64, N_KV, B), 512 threads = 8 waves.
// wave w: q-head = hkv*4 + (w&3), q-rows = qt*64 + (w>>2)*32 + [0,32).
// All 8 waves share the staged K/V tiles (4 q-heads x 2 q-halves).
// Swapped QK^T (S^T in regs, lane-local softmax), exp2 domain, defer-max,
// double-buffered K/V staging, wave-uniform mask hoisting, LDS P roundtrip.

__global__ __launch_bounds__(512, 2)
void attn_kernel(const unsigned short* __restrict__ qkv,
                 const unsigned short* __restrict__ vt,
                 unsigned short* __restrict__ aout) {
    const int qt = blockIdx.x, hkv = blockIdx.y, b = blockIdx.z;
    const int tid = threadIdx.x, lane = tid & 63, w = tid >> 6;
    const int qh = hkv * 4 + (w & 3);          // q-head for this wave
    const int qsub = w >> 2;                   // 0 or 1: which 32-row half
    const int q0w = qt * 64 + qsub * 32;       // wave's first q-row
    const int lo = lane & 15, hi = lane >> 4;

    __shared__ __align__(16) unsigned short sK[2][64 * 128];   // [key][d], chunk-swizzled
    __shared__ __align__(16) unsigned short sV[2][128 * 64];   // [d][key], chunk-swizzled
    __shared__ __align__(16) unsigned short plds[8][32 * 64];  // per-wave P, [q][key^swz]
    unsigned short* pl = plds[w];

    // Q fragments: 2 q-frags x 4 k-chunks
    bf16x8 qf2[2][4];
#pragma unroll
    for (int f = 0; f < 2; ++f) {
        const unsigned short* qp = qkv + (long)(b * T_SEQ + q0w + f * 16 + lo) * NQKV + qh * HD + hi * 8;
#pragma unroll
        for (int s = 0; s < 4; ++s) qf2[f][s] = *(const bf16x8*)(qp + s * 32);
    }

    f32x4 of[8][2] = {};
    float m_r[2] = { -1e30f, -1e30f };   // running max for q = q0w + f*16 + lo
    float s_r[2] = { 0.f, 0.f };

    int kstart = qt * 64 - (WIN - 1);
    if (kstart < 0) kstart = 0;
    kstart &= ~63;
    const int kend = qt * 64 + 63;

    const unsigned short* kbase = qkv + (long)b * T_SEQ * NQKV + DM + hkv * HD;
    const unsigned short* vbase = vt + (long)(b * N_KV + hkv) * HD * T_SEQ;

    // staging offsets (pre-swizzled global source, linear LDS dest); 512 thr x 2 chunks each
    int kr[2], kc[2], vr[2], vc[2];
#pragma unroll
    for (int u = 0; u < 2; ++u) {
        const int c = u * 512 + tid;
        kr[u] = c >> 4;  kc[u] = (c & 15) ^ (kr[u] & 7);   // sK: 16 chunks/row
        vr[u] = c >> 3;  vc[u] = (c & 7) ^ (vr[u] & 7);    // sV: 8 chunks/row
    }

#define STAGE(bf, kt_) do {                                                              \
    _Pragma("unroll")                                                                    \
    for (int u = 0; u < 2; ++u) {                                                        \
        const int dbase = (u * 512 + w * 64) * 8;                                        \
        GLOAD_LDS16(kbase + (long)((kt_) + kr[u]) * NQKV + kc[u] * 8, &sK[bf][dbase]);   \
        GLOAD_LDS16(vbase + (long)vr[u] * T_SEQ + (kt_) + vc[u] * 8, &sV[bf][dbase]);    \
    } } while (0)

    STAGE(0, kstart);
    asm volatile("s_waitcnt vmcnt(0)" ::: "memory");
    __syncthreads();

    int buf = 0;
    for (int kt = kstart; kt <= kend; kt += 64) {
        if (kt + 64 <= kend) STAGE(buf ^ 1, kt + 64);

        // ---- swapped QK^T: sf[n][f] = S^T[key = kt+n*16+hi*4+r][q = q0w+f*16+lo] ----
        f32x4 sf[4][2] = {};
        __builtin_amdgcn_s_setprio(1);
#pragma unroll
        for (int n = 0; n < 4; ++n) {
            const int row = n * 16 + lo;
#pragma unroll
            for (int s = 0; s < 4; ++s) {
                const int c = (s * 4 + hi) ^ (row & 7);
                bf16x8 kf = *(const bf16x8*)&sK[buf][row * 128 + c * 8];
                sf[n][0] = __builtin_amdgcn_mfma_f32_16x16x32_bf16(kf, qf2[0][s], sf[n][0], 0, 0, 0);
                sf[n][1] = __builtin_amdgcn_mfma_f32_16x16x32_bf16(kf, qf2[1][s], sf[n][1], 0, 0, 0);
            }
        }
        __builtin_amdgcn_s_setprio(0);

        // ---- wave-uniform mask hoisting: interior tiles skip all masking ----
        const bool nomask = ((kt + 63) <= q0w) && ((q0w + 31 - kt) < WIN);

        // ---- lane-local online softmax, 2 q-frags ----
        float pv[2][4][4];
        float mx[2] = { -1e30f, -1e30f };
        if (nomask) {
#pragma unroll
            for (int f = 0; f < 2; ++f)
#pragma unroll
                for (int n = 0; n < 4; ++n)
#pragma unroll
                    for (int r = 0; r < 4; ++r) {
                        pv[f][n][r] = sf[n][f][r];
                        mx[f] = fmaxf(mx[f], pv[f][n][r]);
                    }
        } else {
#pragma unroll
            for (int f = 0; f < 2; ++f) {
                const int q = q0w + f * 16 + lo;
#pragma unroll
                for (int n = 0; n < 4; ++n)
#pragma unroll
                    for (int r = 0; r < 4; ++r) {
                        const int d = q - (kt + n * 16 + hi * 4 + r);
                        pv[f][n][r] = (d >= 0 && d < WIN) ? sf[n][f][r] : -1e30f;
                        mx[f] = fmaxf(mx[f], pv[f][n][r]);
                    }
            }
        }
#pragma unroll
        for (int f = 0; f < 2; ++f) {
            mx[f] = fmaxf(mx[f], __shfl_xor(mx[f], 16));
            mx[f] = fmaxf(mx[f], __shfl_xor(mx[f], 32));
        }

        const bool ok = (mx[0] <= m_r[0] + 8.0f) && (mx[1] <= m_r[1] + 8.0f);
        if (!__all(ok)) {                          // defer-max: rescale rarely
#pragma unroll
            for (int f = 0; f < 2; ++f) {
                const float mnew = fmaxf(m_r[f], mx[f]);
                const float resc = exp2f(m_r[f] - mnew);
                s_r[f] *= resc;
                m_r[f] = mnew;
                float r4[4];
#pragma unroll
                for (int r = 0; r < 4; ++r) r4[r] = __shfl(resc, hi * 4 + r);
#pragma unroll
                for (int j = 0; j < 8; ++j) {
                    of[j][f][0] *= r4[0]; of[j][f][1] *= r4[1];
                    of[j][f][2] *= r4[2]; of[j][f][3] *= r4[3];
                }
            }
        }

#pragma unroll
        for (int f = 0; f < 2; ++f) {
            float psum = 0.f;
#pragma unroll
            for (int n = 0; n < 4; ++n)
#pragma unroll
                for (int r = 0; r < 4; ++r) {
                    pv[f][n][r] = exp2f(pv[f][n][r] - m_r[f]);
                    psum += pv[f][n][r];
                }
            psum += __shfl_xor(psum, 16);
            psum += __shfl_xor(psum, 32);
            s_r[f] += psum;
        }

        // ---- pack P -> per-wave swizzled LDS (u32 writes, cvt_pk) ----
        const int swz = (lo & 7) << 3;
#pragma unroll
        for (int f = 0; f < 2; ++f) {
            const int rowq = f * 16 + lo;
#pragma unroll
            for (int n = 0; n < 4; ++n) {
                const int k0 = n * 16 + hi * 4;
                *(unsigned*)&pl[rowq * 64 + (k0 ^ swz)]       = cvt_pk_bf16(pv[f][n][0], pv[f][n][1]);
                *(unsigned*)&pl[rowq * 64 + ((k0 + 2) ^ swz)] = cvt_pk_bf16(pv[f][n][2], pv[f][n][3]);
            }
        }
        asm volatile("s_waitcnt lgkmcnt(0)" ::: "memory");
        __builtin_amdgcn_sched_barrier(0);
        bf16x8 pa2[2][2];
#pragma unroll
        for (int f = 0; f < 2; ++f)
#pragma unroll
            for (int ks = 0; ks < 2; ++ks) {
                const int c = (ks * 4 + hi) ^ (lo & 7);
                pa2[f][ks] = *(const bf16x8*)&pl[(f * 16 + lo) * 64 + c * 8];
            }

        // ---- PV: of[j][f] += P[q-frag f] . V[d=j*16+lo] ----
        __builtin_amdgcn_s_setprio(1);
#pragma unroll
        for (int j = 0; j < 8; ++j) {
            const int row = j * 16 + lo;
#pragma unroll
            for (int ks = 0; ks < 2; ++ks) {
                const int c = (ks * 4 + hi) ^ (row & 7);
                bf16x8 vf = *(const bf16x8*)&sV[buf][row * 64 + c * 8];
                of[j][0] = __builtin_amdgcn_mfma_f32_16x16x32_bf16(pa2[0][ks], vf, of[j][0], 0, 0, 0);
                of[j][1] = __builtin_amdgcn_mfma_f32_16x16x32_bf16(pa2[1][ks], vf, of[j][1], 0, 0, 0);
            }
        }
        __builtin_amdgcn_s_setprio(0);

        asm volatile("s_waitcnt vmcnt(0)" ::: "memory");
        __syncthreads();
        buf ^= 1;
    }
#undef STAGE

#pragma unroll
    for (int f = 0; f < 2; ++f) {
        float s4[4];
#pragma unroll
        for (int r = 0; r < 4; ++r) s4[r] = __shfl(s_r[f], hi * 4 + r);
#pragma unroll
        for (int r = 0; r < 4; ++r) {
            const int qrow = q0w + f * 16 + hi * 4 + r;
            const float inv = 1.0f / s4[r];
            unsigned short* op = aout + (long)(b * T_SEQ + qrow) * DM + qh * HD + lo;
#pragma unroll
            for (int j = 0; j < 8; ++j) op[j * 16] = f2bf(of[j][f][r] * inv);
        }
    }
}

// ---------------- launch ----------------

extern "C" void kernel_launch(void* const* d_in, const int* in_sizes, int n_in,
                              void* d_out, int out_size, void* d_ws, size_t ws_size,
                              hipStream_t stream) {
    (void)in_sizes; (void)n_in; (void)out_size; (void)ws_size;
    const float* x  = (const float*)d_in[0];
    const float* wq = (const float*)d_in[1];
    const float* wk = (const float*)d_in[2];
    const float* wv = (const float*)d_in[3];
    const float* wo = (const float*)d_in[4];
    float* out = (float*)d_out;
    char* ws = (char*)d_ws;

    unsigned short* xbf   = (unsigned short*)(ws);                // 16,777,216 B
    unsigned short* wqkvT = (unsigned short*)(ws + 16777216);     // 12,582,912 B
    unsigned short* woT   = (unsigned short*)(ws + 29360128);     //  8,388,608 B
    unsigned short* qkv   = (unsigned short*)(ws + 37748736);     // 25,165,824 B
    unsigned short* vt    = (unsigned short*)(ws + 62914560);     //  4,194,304 B
    unsigned short* aout  = (unsigned short*)(ws + 67108864);     // 16,777,216 B
    float* cosT = (float*)(ws + 83886080);                        //    524,288 B
    float* sinT = (float*)(ws + 84410368);                        //    524,288 B

    prep_a<<<dim3(18944), dim3(256), 0, stream>>>(x, wq, wk, wv, wo, xbf, wqkvT, woT, cosT, sinT);
    gemm_qkv<<<dim3(NQKV / 128, 32), dim3(256), 0, stream>>>(xbf, wqkvT, qkv, cosT, sinT);
    prep_b<<<dim3(2048), dim3(256), 0, stream>>>(qkv, vt);
    attn_kernel<<<dim3(T_SEQ / 64, 4, 2), dim3(512), 0, stream>>>(qkv, vt, aout);
    gemm_bt<<<dim3(DM / 128, 32), dim3(256), 0, stream>>>(aout, woT, out, DM, DM);
}

// Round 14
// 162.821 us; speedup vs baseline: 1.0798x; 1.0798x over previous
//
#include <hip/hip_runtime.h>

#define T_SEQ   2048
#define DM      2048
#define N_Q     16
#define N_KV    4
#define HD      128
#define WIN     512
#define NB      2
#define NQKV    3072
// 1/sqrt(128) * log2(e): attention computed in exp2 domain
#define QK_SCALE_L2E 0.12751744f

typedef short bf16x8 __attribute__((ext_vector_type(8)));
typedef float f32x4  __attribute__((ext_vector_type(4)));
typedef float f32x16 __attribute__((ext_vector_type(16)));
typedef unsigned short us4v __attribute__((ext_vector_type(4)));

__device__ __forceinline__ unsigned short f2bf(float f) {
    union { float f; unsigned u; } v; v.f = f;
    unsigned u = v.u;
    u += 0x7fffu + ((u >> 16) & 1u);           // RNE
    return (unsigned short)(u >> 16);
}
__device__ __forceinline__ float bf2f(unsigned short h) {
    union { unsigned u; float f; } v; v.u = ((unsigned)h) << 16;
    return v.f;
}
__device__ __forceinline__ unsigned cvt_pk_bf16(float a, float b) {
    unsigned r;
    asm("v_cvt_pk_bf16_f32 %0, %1, %2" : "=v"(r) : "v"(a), "v"(b));
    return r;   // low16 = bf16(a), high16 = bf16(b)
}

#define GLOAD_LDS16(g, l) __builtin_amdgcn_global_load_lds( \
    (const __attribute__((address_space(1))) void*)(g),     \
    (__attribute__((address_space(3))) void*)(l), 16, 0, 0)

struct us4 { unsigned short a, b, c, d; };

// ---------------- fused prep A: x->bf16, 4 weight transposes, rope table ----------------
// flat grid: [0,8192) x-convert | [8192,18432) transposes | [18432,18944) rope table

__global__ __launch_bounds__(256)
void prep_a(const float* __restrict__ x, const float* __restrict__ wq,
            const float* __restrict__ wk, const float* __restrict__ wv,
            const float* __restrict__ wo,
            unsigned short* __restrict__ xbf, unsigned short* __restrict__ wqkvT,
            unsigned short* __restrict__ woT,
            float* __restrict__ cosT, float* __restrict__ sinT) {
    __shared__ float tile[32][33];
    int blk = blockIdx.x;
    if (blk < 8192) {                               // x: f32 -> bf16, 4 elems/thread
        long i = ((long)blk * 256 + threadIdx.x) * 4;
        float4 f = *(const float4*)(x + i);
        us4 o; o.a = f2bf(f.x); o.b = f2bf(f.y); o.c = f2bf(f.z); o.d = f2bf(f.w);
        *(us4*)(xbf + i) = o;
        return;
    }
    blk -= 8192;
    if (blk < 10240) {                              // weight transposes
        const float* in; unsigned short* outp; int C, bx, by;
        if (blk < 4096)      { in = wq; outp = wqkvT;                         C = DM;  bx = blk & 63;          by = blk >> 6; }
        else if (blk < 5120) { int k = blk - 4096; in = wk; outp = wqkvT + (long)DM * DM;         C = 512; bx = k & 15; by = k >> 4; }
        else if (blk < 6144) { int k = blk - 5120; in = wv; outp = wqkvT + (long)(DM + 512) * DM; C = 512; bx = k & 15; by = k >> 4; }
        else                 { int k = blk - 6144; in = wo; outp = woT;                           C = DM;  bx = k & 63; by = k >> 6; }
        const int c0 = bx * 32, r0 = by * 32;
        const int tx = threadIdx.x & 31, ty = threadIdx.x >> 5;
#pragma unroll
        for (int i = 0; i < 4; ++i)
            tile[ty + i * 8][tx] = in[(long)(r0 + ty + i * 8) * C + c0 + tx];
        __syncthreads();
#pragma unroll
        for (int i = 0; i < 4; ++i)
            outp[(long)(c0 + ty + i * 8) * DM + r0 + tx] = f2bf(tile[tx][ty + i * 8]);
        return;
    }
    blk -= 10240;                                   // rope table (512 blocks)
    const int idx = blk * 256 + threadIdx.x;        // < 2048*64
    const int t = idx >> 6, d = idx & 63;
    const float inv = __expf(-(float)d * (9.210340371976184f / 64.0f)); // 10000^(-d/64)
    const float ang = (float)t * inv;
    cosT[idx] = cosf(ang);
    sinT[idx] = sinf(ang);
}

// ---------------- prep B: rope apply (q,k) only — v goes transposed straight
// from the qkv GEMM epilogue. 5120 blocks, 4 d-values/thread.

__global__ __launch_bounds__(256)
void prep_b(unsigned short* __restrict__ qkv,
            const float* __restrict__ cosT, const float* __restrict__ sinT) {
    const int idx = blockIdx.x * 256 + threadIdx.x;    // 4096*20*16
    const int d4 = (idx & 15) * 4;
    const int hh = (idx >> 4) % 20;
    const int row = idx / (16 * 20);
    const int t = row & (T_SEQ - 1);
    const int col = (hh < N_Q) ? hh * HD + d4 : DM + (hh - N_Q) * HD + d4;
    unsigned short* p = qkv + (long)row * NQKV + col;
    us4v a = *(const us4v*)p;
    us4v b = *(const us4v*)(p + 64);
    float4 c = *(const float4*)&cosT[t * 64 + d4];
    float4 s = *(const float4*)&sinT[t * 64 + d4];
    const float sc = (hh < N_Q) ? QK_SCALE_L2E : 1.0f;
    us4v o1, o2;
    const float cc[4] = { c.x, c.y, c.z, c.w }, ss[4] = { s.x, s.y, s.z, s.w };
#pragma unroll
    for (int i = 0; i < 4; ++i) {
        const float av = bf2f(a[i]), bv = bf2f(b[i]);
        o1[i] = f2bf((av * cc[i] - bv * ss[i]) * sc);
        o2[i] = f2bf((bv * cc[i] + av * ss[i]) * sc);
    }
    *(us4v*)p        = o1;
    *(us4v*)(p + 64) = o2;
}

// ---------------- GEMM: C[M][ldc] = A[M][K] * Bt[N][K]^T ----------------
// m97 structure, 32x32x16 MFMA. For OUT_BF16 (qkv projection): v col-blocks
// (hb>=20, block-uniform) write DIRECTLY to vt[b][hkv][d][t] (transposed) —
// address arithmetic only, no extra live state; t is consecutive within each
// r-quad so stores coalesce to 8B runs. q/k blocks write qkv as before.
// C/D map (HW-verified m74/m101): col=lane&31, row=(r&3)+8*(r>>2)+4*(lane>>5).

template<int OUT_BF16>
__global__ __launch_bounds__(256)
void gemm_bt(const unsigned short* __restrict__ A,
             const unsigned short* __restrict__ Bt,
             void* __restrict__ Cvoid, int K, int ldc,
             unsigned short* __restrict__ vt) {
    __shared__ __align__(16) unsigned short sA[128 * 64];
    __shared__ __align__(16) unsigned short sB[128 * 64];
    const int tid = threadIdx.x;
    const int lane = tid & 63;
    const int wid = tid >> 6;
    const int wr = (wid >> 1) * 64, wc = (wid & 1) * 64;
    const int l5 = lane >> 5, l31 = lane & 31;

    // XCD-aware bijective swizzle (nwg divisible by 8 in all launches)
    const int gx = gridDim.x;
    const int nwg = gx * gridDim.y;
    int flat = blockIdx.y * gx + blockIdx.x;
    flat = (flat & 7) * (nwg >> 3) + (flat >> 3);
    const long Arow0 = (long)(flat / gx) * 128;
    const long Brow0 = (long)(flat % gx) * 128;

    f32x16 acc[2][2] = {};

    for (int kt = 0; kt < K; kt += 64) {
        __syncthreads();
#pragma unroll
        for (int n = 0; n < 4; ++n) {
            const int linb = n * 256 + wid * 64;      // wave-uniform 16B-chunk base
            const int lin  = linb + lane;             // this lane's chunk
            const int row  = lin >> 3;                // 8 chunks per 64-elem row
            const int sw   = (row ^ (row >> 3)) & 7;
            const int sc   = (lin & 7) ^ sw;          // pre-swizzled global source
            const unsigned short* gA = A  + (Arow0 + row) * K + kt + sc * 8;
            const unsigned short* gB = Bt + (Brow0 + row) * K + kt + sc * 8;
            GLOAD_LDS16(gA, &sA[linb * 8]);
            GLOAD_LDS16(gB, &sB[linb * 8]);
        }
        __syncthreads();
#pragma unroll
        for (int kc = 0; kc < 4; ++kc) {
            bf16x8 av[2], bv[2];
#pragma unroll
            for (int t = 0; t < 2; ++t) {
                const int rowa = wr + t * 32 + l31;
                const int ca = (kc * 2 + l5) ^ ((rowa ^ (rowa >> 3)) & 7);
                av[t] = *(const bf16x8*)&sA[rowa * 64 + ca * 8];
                const int rowb = wc + t * 32 + l31;
                const int cb = (kc * 2 + l5) ^ ((rowb ^ (rowb >> 3)) & 7);
                bv[t] = *(const bf16x8*)&sB[rowb * 64 + cb * 8];
            }
#pragma unroll
            for (int ti = 0; ti < 2; ++ti)
#pragma unroll
                for (int tj = 0; tj < 2; ++tj)
                    acc[ti][tj] = __builtin_amdgcn_mfma_f32_32x32x16_bf16(av[ti], bv[tj], acc[ti][tj], 0, 0, 0);
        }
    }

    if (OUT_BF16) {
        const int hb = (int)(Brow0 >> 7);            // 0-15 q, 16-19 k, 20-23 v
        unsigned short* C = (unsigned short*)Cvoid;
        if (hb >= 20) {
            // v: write transposed into vt[(b*4+hkv)*128 + d][t]
            const long bb = Arow0 >> 11;             // batch (uniform per block)
            const int hkv = hb - 20;
#pragma unroll
            for (int ti = 0; ti < 2; ++ti)
#pragma unroll
                for (int tj = 0; tj < 2; ++tj) {
                    const int d = wc + tj * 32 + l31;
                    unsigned short* vp = vt + ((bb * 4 + hkv) * 128 + d) * (long)T_SEQ;
#pragma unroll
                    for (int r = 0; r < 16; ++r) {
                        const int t = (int)((Arow0 + wr + ti * 32 + (r & 3) + 8 * (r >> 2) + 4 * l5) & (T_SEQ - 1));
                        vp[t] = f2bf(acc[ti][tj][r]);
                    }
                }
        } else {
#pragma unroll
            for (int ti = 0; ti < 2; ++ti)
#pragma unroll
                for (int tj = 0; tj < 2; ++tj)
#pragma unroll
                    for (int r = 0; r < 16; ++r) {
                        const long row = Arow0 + wr + ti * 32 + (r & 3) + 8 * (r >> 2) + 4 * l5;
                        const long col = Brow0 + wc + tj * 32 + l31;
                        C[row * ldc + col] = f2bf(acc[ti][tj][r]);
                    }
        }
    } else {
        float* C = (float*)Cvoid;
#pragma unroll
        for (int ti = 0; ti < 2; ++ti)
#pragma unroll
            for (int tj = 0; tj < 2; ++tj)
#pragma unroll
                for (int r = 0; r < 16; ++r) {
                    const long row = Arow0 + wr + ti * 32 + (r & 3) + 8 * (r >> 2) + 4 * l5;
                    const long col = Brow0 + wc + tj * 32 + l31;
                    C[row * ldc + col] = acc[ti][tj][r];
                }
    }
}

// ---------------- flash attention, sliding window ----------------
// grid (T/64, N_KV, B), 512 threads = 8 waves.
// wave w: q-head = hkv*4 + (w&3), q-rows = qt*64 + (w>>2)*32 + [0,32).
// All 8 waves share the staged K/V tiles (4 q-heads x 2 q-halves).
// Swapped QK^T (S^T in regs, lane-local softmax), exp2 domain, defer-max,
// double-buffered K/V staging, wave-uniform mask hoisting, LDS P roundtrip.

__global__ __launch_bounds__(512, 2)
void attn_kernel(const unsigned short* __restrict__ qkv,
                 const unsigned short* __restrict__ vt,
                 unsigned short* __restrict__ aout) {
    const int qt = blockIdx.x, hkv = blockIdx.y, b = blockIdx.z;
    const int tid = threadIdx.x, lane = tid & 63, w = tid >> 6;
    const int qh = hkv * 4 + (w & 3);          // q-head for this wave
    const int qsub = w >> 2;                   // 0 or 1: which 32-row half
    const int q0w = qt * 64 + qsub * 32;       // wave's first q-row
    const int lo = lane & 15, hi = lane >> 4;

    __shared__ __align__(16) unsigned short sK[2][64 * 128];   // [key][d], chunk-swizzled
    __shared__ __align__(16) unsigned short sV[2][128 * 64];   // [d][key], chunk-swizzled
    __shared__ __align__(16) unsigned short plds[8][32 * 64];  // per-wave P, [q][key^swz]
    unsigned short* pl = plds[w];

    // Q fragments: 2 q-frags x 4 k-chunks
    bf16x8 qf2[2][4];
#pragma unroll
    for (int f = 0; f < 2; ++f) {
        const unsigned short* qp = qkv + (long)(b * T_SEQ + q0w + f * 16 + lo) * NQKV + qh * HD + hi * 8;
#pragma unroll
        for (int s = 0; s < 4; ++s) qf2[f][s] = *(const bf16x8*)(qp + s * 32);
    }

    f32x4 of[8][2] = {};
    float m_r[2] = { -1e30f, -1e30f };   // running max for q = q0w + f*16 + lo
    float s_r[2] = { 0.f, 0.f };

    int kstart = qt * 64 - (WIN - 1);
    if (kstart < 0) kstart = 0;
    kstart &= ~63;
    const int kend = qt * 64 + 63;

    const unsigned short* kbase = qkv + (long)b * T_SEQ * NQKV + DM + hkv * HD;
    const unsigned short* vbase = vt + (long)(b * N_KV + hkv) * HD * T_SEQ;

    // staging offsets (pre-swizzled global source, linear LDS dest); 512 thr x 2 chunks each
    int kr[2], kc[2], vr[2], vc[2];
#pragma unroll
    for (int u = 0; u < 2; ++u) {
        const int c = u * 512 + tid;
        kr[u] = c >> 4;  kc[u] = (c & 15) ^ (kr[u] & 7);   // sK: 16 chunks/row
        vr[u] = c >> 3;  vc[u] = (c & 7) ^ (vr[u] & 7);    // sV: 8 chunks/row
    }

#define STAGE(bf, kt_) do {                                                              \
    _Pragma("unroll")                                                                    \
    for (int u = 0; u < 2; ++u) {                                                        \
        const int dbase = (u * 512 + w * 64) * 8;                                        \
        GLOAD_LDS16(kbase + (long)((kt_) + kr[u]) * NQKV + kc[u] * 8, &sK[bf][dbase]);   \
        GLOAD_LDS16(vbase + (long)vr[u] * T_SEQ + (kt_) + vc[u] * 8, &sV[bf][dbase]);    \
    } } while (0)

    STAGE(0, kstart);
    asm volatile("s_waitcnt vmcnt(0)" ::: "memory");
    __syncthreads();

    int buf = 0;
    for (int kt = kstart; kt <= kend; kt += 64) {
        if (kt + 64 <= kend) STAGE(buf ^ 1, kt + 64);

        // ---- swapped QK^T: sf[n][f] = S^T[key = kt+n*16+hi*4+r][q = q0w+f*16+lo] ----
        f32x4 sf[4][2] = {};
        __builtin_amdgcn_s_setprio(1);
#pragma unroll
        for (int n = 0; n < 4; ++n) {
            const int row = n * 16 + lo;
#pragma unroll
            for (int s = 0; s < 4; ++s) {
                const int c = (s * 4 + hi) ^ (row & 7);
                bf16x8 kf = *(const bf16x8*)&sK[buf][row * 128 + c * 8];
                sf[n][0] = __builtin_amdgcn_mfma_f32_16x16x32_bf16(kf, qf2[0][s], sf[n][0], 0, 0, 0);
                sf[n][1] = __builtin_amdgcn_mfma_f32_16x16x32_bf16(kf, qf2[1][s], sf[n][1], 0, 0, 0);
            }
        }
        __builtin_amdgcn_s_setprio(0);

        // ---- wave-uniform mask hoisting: interior tiles skip all masking ----
        const bool nomask = ((kt + 63) <= q0w) && ((q0w + 31 - kt) < WIN);

        // ---- lane-local online softmax, 2 q-frags ----
        float pv[2][4][4];
        float mx[2] = { -1e30f, -1e30f };
        if (nomask) {
#pragma unroll
            for (int f = 0; f < 2; ++f)
#pragma unroll
                for (int n = 0; n < 4; ++n)
#pragma unroll
                    for (int r = 0; r < 4; ++r) {
                        pv[f][n][r] = sf[n][f][r];
                        mx[f] = fmaxf(mx[f], pv[f][n][r]);
                    }
        } else {
#pragma unroll
            for (int f = 0; f < 2; ++f) {
                const int q = q0w + f * 16 + lo;
#pragma unroll
                for (int n = 0; n < 4; ++n)
#pragma unroll
                    for (int r = 0; r < 4; ++r) {
                        const int d = q - (kt + n * 16 + hi * 4 + r);
                        pv[f][n][r] = (d >= 0 && d < WIN) ? sf[n][f][r] : -1e30f;
                        mx[f] = fmaxf(mx[f], pv[f][n][r]);
                    }
            }
        }
#pragma unroll
        for (int f = 0; f < 2; ++f) {
            mx[f] = fmaxf(mx[f], __shfl_xor(mx[f], 16));
            mx[f] = fmaxf(mx[f], __shfl_xor(mx[f], 32));
        }

        const bool ok = (mx[0] <= m_r[0] + 8.0f) && (mx[1] <= m_r[1] + 8.0f);
        if (!__all(ok)) {                          // defer-max: rescale rarely
#pragma unroll
            for (int f = 0; f < 2; ++f) {
                const float mnew = fmaxf(m_r[f], mx[f]);
                const float resc = exp2f(m_r[f] - mnew);
                s_r[f] *= resc;
                m_r[f] = mnew;
                float r4[4];
#pragma unroll
                for (int r = 0; r < 4; ++r) r4[r] = __shfl(resc, hi * 4 + r);
#pragma unroll
                for (int j = 0; j < 8; ++j) {
                    of[j][f][0] *= r4[0]; of[j][f][1] *= r4[1];
                    of[j][f][2] *= r4[2]; of[j][f][3] *= r4[3];
                }
            }
        }

#pragma unroll
        for (int f = 0; f < 2; ++f) {
            float psum = 0.f;
#pragma unroll
            for (int n = 0; n < 4; ++n)
#pragma unroll
                for (int r = 0; r < 4; ++r) {
                    pv[f][n][r] = exp2f(pv[f][n][r] - m_r[f]);
                    psum += pv[f][n][r];
                }
            psum += __shfl_xor(psum, 16);
            psum += __shfl_xor(psum, 32);
            s_r[f] += psum;
        }

        // ---- pack P -> per-wave swizzled LDS (u32 writes, cvt_pk) ----
        const int swz = (lo & 7) << 3;
#pragma unroll
        for (int f = 0; f < 2; ++f) {
            const int rowq = f * 16 + lo;
#pragma unroll
            for (int n = 0; n < 4; ++n) {
                const int k0 = n * 16 + hi * 4;
                *(unsigned*)&pl[rowq * 64 + (k0 ^ swz)]       = cvt_pk_bf16(pv[f][n][0], pv[f][n][1]);
                *(unsigned*)&pl[rowq * 64 + ((k0 + 2) ^ swz)] = cvt_pk_bf16(pv[f][n][2], pv[f][n][3]);
            }
        }
        asm volatile("s_waitcnt lgkmcnt(0)" ::: "memory");
        __builtin_amdgcn_sched_barrier(0);
        bf16x8 pa2[2][2];
#pragma unroll
        for (int f = 0; f < 2; ++f)
#pragma unroll
            for (int ks = 0; ks < 2; ++ks) {
                const int c = (ks * 4 + hi) ^ (lo & 7);
                pa2[f][ks] = *(const bf16x8*)&pl[(f * 16 + lo) * 64 + c * 8];
            }

        // ---- PV: of[j][f] += P[q-frag f] . V[d=j*16+lo] ----
        __builtin_amdgcn_s_setprio(1);
#pragma unroll
        for (int j = 0; j < 8; ++j) {
            const int row = j * 16 + lo;
#pragma unroll
            for (int ks = 0; ks < 2; ++ks) {
                const int c = (ks * 4 + hi) ^ (row & 7);
                bf16x8 vf = *(const bf16x8*)&sV[buf][row * 64 + c * 8];
                of[j][0] = __builtin_amdgcn_mfma_f32_16x16x32_bf16(pa2[0][ks], vf, of[j][0], 0, 0, 0);
                of[j][1] = __builtin_amdgcn_mfma_f32_16x16x32_bf16(pa2[1][ks], vf, of[j][1], 0, 0, 0);
            }
        }
        __builtin_amdgcn_s_setprio(0);

        asm volatile("s_waitcnt vmcnt(0)" ::: "memory");
        __syncthreads();
        buf ^= 1;
    }
#undef STAGE

#pragma unroll
    for (int f = 0; f < 2; ++f) {
        float s4[4];
#pragma unroll
        for (int r = 0; r < 4; ++r) s4[r] = __shfl(s_r[f], hi * 4 + r);
#pragma unroll
        for (int r = 0; r < 4; ++r) {
            const int qrow = q0w + f * 16 + hi * 4 + r;
            const float inv = 1.0f / s4[r];
            unsigned short* op = aout + (long)(b * T_SEQ + qrow) * DM + qh * HD + lo;
#pragma unroll
            for (int j = 0; j < 8; ++j) op[j * 16] = f2bf(of[j][f][r] * inv);
        }
    }
}

// ---------------- launch ----------------

extern "C" void kernel_launch(void* const* d_in, const int* in_sizes, int n_in,
                              void* d_out, int out_size, void* d_ws, size_t ws_size,
                              hipStream_t stream) {
    (void)in_sizes; (void)n_in; (void)out_size; (void)ws_size;
    const float* x  = (const float*)d_in[0];
    const float* wq = (const float*)d_in[1];
    const float* wk = (const float*)d_in[2];
    const float* wv = (const float*)d_in[3];
    const float* wo = (const float*)d_in[4];
    float* out = (float*)d_out;
    char* ws = (char*)d_ws;

    unsigned short* xbf   = (unsigned short*)(ws);                // 16,777,216 B
    unsigned short* wqkvT = (unsigned short*)(ws + 16777216);     // 12,582,912 B
    unsigned short* woT   = (unsigned short*)(ws + 29360128);     //  8,388,608 B
    unsigned short* qkv   = (unsigned short*)(ws + 37748736);     // 25,165,824 B
    unsigned short* vt    = (unsigned short*)(ws + 62914560);     //  4,194,304 B
    unsigned short* aout  = (unsigned short*)(ws + 67108864);     // 16,777,216 B
    float* cosT = (float*)(ws + 83886080);                        //    524,288 B
    float* sinT = (float*)(ws + 84410368);                        //    524,288 B

    prep_a<<<dim3(18944), dim3(256), 0, stream>>>(x, wq, wk, wv, wo, xbf, wqkvT, woT, cosT, sinT);
    gemm_bt<1><<<dim3(NQKV / 128, 32), dim3(256), 0, stream>>>(xbf, wqkvT, qkv, DM, NQKV, vt);
    prep_b<<<dim3(5120), dim3(256), 0, stream>>>(qkv, cosT, sinT);
    attn_kernel<<<dim3(T_SEQ / 64, 4, 2), dim3(512), 0, stream>>>(qkv, vt, aout);
    gemm_bt<0><<<dim3(DM / 128, 32), dim3(256), 0, stream>>>(aout, woT, out, DM, DM, nullptr);
}

// Round 15
// 162.783 us; speedup vs baseline: 1.0801x; 1.0002x over previous
//
#include <hip/hip_runtime.h>

#define T_SEQ   2048
#define DM      2048
#define N_Q     16
#define N_KV    4
#define HD      128
#define WIN     512
#define NB      2
#define NQKV    3072
// 1/sqrt(128) * log2(e): attention computed in exp2 domain
#define QK_SCALE_L2E 0.12751744f

typedef short bf16x8 __attribute__((ext_vector_type(8)));
typedef float f32x4  __attribute__((ext_vector_type(4)));
typedef float f32x16 __attribute__((ext_vector_type(16)));
typedef unsigned short us4v __attribute__((ext_vector_type(4)));

__device__ __forceinline__ unsigned short f2bf(float f) {
    union { float f; unsigned u; } v; v.f = f;
    unsigned u = v.u;
    u += 0x7fffu + ((u >> 16) & 1u);           // RNE
    return (unsigned short)(u >> 16);
}
__device__ __forceinline__ float bf2f(unsigned short h) {
    union { unsigned u; float f; } v; v.u = ((unsigned)h) << 16;
    return v.f;
}
__device__ __forceinline__ unsigned cvt_pk_bf16(float a, float b) {
    unsigned r;
    asm("v_cvt_pk_bf16_f32 %0, %1, %2" : "=v"(r) : "v"(a), "v"(b));
    return r;   // low16 = bf16(a), high16 = bf16(b)
}

#define GLOAD_LDS16(g, l) __builtin_amdgcn_global_load_lds( \
    (const __attribute__((address_space(1))) void*)(g),     \
    (__attribute__((address_space(3))) void*)(l), 16, 0, 0)

struct us4 { unsigned short a, b, c, d; };

// ---------------- fused prep A: x->bf16, 4 weight transposes, rope table ----------------
// flat grid: [0,8192) x-convert | [8192,18432) transposes | [18432,18944) rope table

__global__ __launch_bounds__(256)
void prep_a(const float* __restrict__ x, const float* __restrict__ wq,
            const float* __restrict__ wk, const float* __restrict__ wv,
            const float* __restrict__ wo,
            unsigned short* __restrict__ xbf, unsigned short* __restrict__ wqkvT,
            unsigned short* __restrict__ woT,
            float* __restrict__ cosT, float* __restrict__ sinT) {
    __shared__ float tile[32][33];
    int blk = blockIdx.x;
    if (blk < 8192) {                               // x: f32 -> bf16, 4 elems/thread
        long i = ((long)blk * 256 + threadIdx.x) * 4;
        float4 f = *(const float4*)(x + i);
        us4 o; o.a = f2bf(f.x); o.b = f2bf(f.y); o.c = f2bf(f.z); o.d = f2bf(f.w);
        *(us4*)(xbf + i) = o;
        return;
    }
    blk -= 8192;
    if (blk < 10240) {                              // weight transposes
        const float* in; unsigned short* outp; int C, bx, by;
        if (blk < 4096)      { in = wq; outp = wqkvT;                         C = DM;  bx = blk & 63;          by = blk >> 6; }
        else if (blk < 5120) { int k = blk - 4096; in = wk; outp = wqkvT + (long)DM * DM;         C = 512; bx = k & 15; by = k >> 4; }
        else if (blk < 6144) { int k = blk - 5120; in = wv; outp = wqkvT + (long)(DM + 512) * DM; C = 512; bx = k & 15; by = k >> 4; }
        else                 { int k = blk - 6144; in = wo; outp = woT;                           C = DM;  bx = k & 63; by = k >> 6; }
        const int c0 = bx * 32, r0 = by * 32;
        const int tx = threadIdx.x & 31, ty = threadIdx.x >> 5;
#pragma unroll
        for (int i = 0; i < 4; ++i)
            tile[ty + i * 8][tx] = in[(long)(r0 + ty + i * 8) * C + c0 + tx];
        __syncthreads();
#pragma unroll
        for (int i = 0; i < 4; ++i)
            outp[(long)(c0 + ty + i * 8) * DM + r0 + tx] = f2bf(tile[tx][ty + i * 8]);
        return;
    }
    blk -= 10240;                                   // rope table (512 blocks)
    const int idx = blk * 256 + threadIdx.x;        // < 2048*64
    const int t = idx >> 6, d = idx & 63;
    const float inv = __expf(-(float)d * (9.210340371976184f / 64.0f)); // 10000^(-d/64)
    const float ang = (float)t * inv;
    cosT[idx] = cosf(ang);
    sinT[idx] = sinf(ang);
}

// ---------------- prep B: rope apply on K only (q-rope fused into attn,
// v written transposed by the qkv GEMM epilogue). 1024 blocks.

__global__ __launch_bounds__(256)
void prep_b(unsigned short* __restrict__ qkv,
            const float* __restrict__ cosT, const float* __restrict__ sinT) {
    const int idx = blockIdx.x * 256 + threadIdx.x;    // 4096 rows * 4 kheads * 16
    const int d4 = (idx & 15) * 4;
    const int hh = (idx >> 4) & 3;
    const int row = idx >> 6;
    const int t = row & (T_SEQ - 1);
    const int col = DM + hh * HD + d4;
    unsigned short* p = qkv + (long)row * NQKV + col;
    us4v a = *(const us4v*)p;
    us4v b = *(const us4v*)(p + 64);
    float4 c = *(const float4*)&cosT[t * 64 + d4];
    float4 s = *(const float4*)&sinT[t * 64 + d4];
    us4v o1, o2;
    const float cc[4] = { c.x, c.y, c.z, c.w }, ss[4] = { s.x, s.y, s.z, s.w };
#pragma unroll
    for (int i = 0; i < 4; ++i) {
        const float av = bf2f(a[i]), bv = bf2f(b[i]);
        o1[i] = f2bf(av * cc[i] - bv * ss[i]);
        o2[i] = f2bf(bv * cc[i] + av * ss[i]);
    }
    *(us4v*)p        = o1;
    *(us4v*)(p + 64) = o2;
}

// ---------------- GEMM: C[M][ldc] = A[M][K] * Bt[N][K]^T ----------------
// m97 structure, 32x32x16 MFMA. For OUT_BF16 (qkv projection): v col-blocks
// (hb>=20, block-uniform) write DIRECTLY to vt[b][hkv][d][t] (transposed).
// C/D map (HW-verified m74/m101): col=lane&31, row=(r&3)+8*(r>>2)+4*(lane>>5).

template<int OUT_BF16>
__global__ __launch_bounds__(256)
void gemm_bt(const unsigned short* __restrict__ A,
             const unsigned short* __restrict__ Bt,
             void* __restrict__ Cvoid, int K, int ldc,
             unsigned short* __restrict__ vt) {
    __shared__ __align__(16) unsigned short sA[128 * 64];
    __shared__ __align__(16) unsigned short sB[128 * 64];
    const int tid = threadIdx.x;
    const int lane = tid & 63;
    const int wid = tid >> 6;
    const int wr = (wid >> 1) * 64, wc = (wid & 1) * 64;
    const int l5 = lane >> 5, l31 = lane & 31;

    // XCD-aware bijective swizzle (nwg divisible by 8 in all launches)
    const int gx = gridDim.x;
    const int nwg = gx * gridDim.y;
    int flat = blockIdx.y * gx + blockIdx.x;
    flat = (flat & 7) * (nwg >> 3) + (flat >> 3);
    const long Arow0 = (long)(flat / gx) * 128;
    const long Brow0 = (long)(flat % gx) * 128;

    f32x16 acc[2][2] = {};

    for (int kt = 0; kt < K; kt += 64) {
        __syncthreads();
#pragma unroll
        for (int n = 0; n < 4; ++n) {
            const int linb = n * 256 + wid * 64;      // wave-uniform 16B-chunk base
            const int lin  = linb + lane;             // this lane's chunk
            const int row  = lin >> 3;                // 8 chunks per 64-elem row
            const int sw   = (row ^ (row >> 3)) & 7;
            const int sc   = (lin & 7) ^ sw;          // pre-swizzled global source
            const unsigned short* gA = A  + (Arow0 + row) * K + kt + sc * 8;
            const unsigned short* gB = Bt + (Brow0 + row) * K + kt + sc * 8;
            GLOAD_LDS16(gA, &sA[linb * 8]);
            GLOAD_LDS16(gB, &sB[linb * 8]);
        }
        __syncthreads();
#pragma unroll
        for (int kc = 0; kc < 4; ++kc) {
            bf16x8 av[2], bv[2];
#pragma unroll
            for (int t = 0; t < 2; ++t) {
                const int rowa = wr + t * 32 + l31;
                const int ca = (kc * 2 + l5) ^ ((rowa ^ (rowa >> 3)) & 7);
                av[t] = *(const bf16x8*)&sA[rowa * 64 + ca * 8];
                const int rowb = wc + t * 32 + l31;
                const int cb = (kc * 2 + l5) ^ ((rowb ^ (rowb >> 3)) & 7);
                bv[t] = *(const bf16x8*)&sB[rowb * 64 + cb * 8];
            }
#pragma unroll
            for (int ti = 0; ti < 2; ++ti)
#pragma unroll
                for (int tj = 0; tj < 2; ++tj)
                    acc[ti][tj] = __builtin_amdgcn_mfma_f32_32x32x16_bf16(av[ti], bv[tj], acc[ti][tj], 0, 0, 0);
        }
    }

    if (OUT_BF16) {
        const int hb = (int)(Brow0 >> 7);            // 0-15 q, 16-19 k, 20-23 v
        unsigned short* C = (unsigned short*)Cvoid;
        if (hb >= 20) {
            // v: write transposed into vt[(b*4+hkv)*128 + d][t]
            const long bb = Arow0 >> 11;             // batch (uniform per block)
            const int hkv = hb - 20;
#pragma unroll
            for (int ti = 0; ti < 2; ++ti)
#pragma unroll
                for (int tj = 0; tj < 2; ++tj) {
                    const int d = wc + tj * 32 + l31;
                    unsigned short* vp = vt + ((bb * 4 + hkv) * 128 + d) * (long)T_SEQ;
#pragma unroll
                    for (int r = 0; r < 16; ++r) {
                        const int t = (int)((Arow0 + wr + ti * 32 + (r & 3) + 8 * (r >> 2) + 4 * l5) & (T_SEQ - 1));
                        vp[t] = f2bf(acc[ti][tj][r]);
                    }
                }
        } else {
#pragma unroll
            for (int ti = 0; ti < 2; ++ti)
#pragma unroll
                for (int tj = 0; tj < 2; ++tj)
#pragma unroll
                    for (int r = 0; r < 16; ++r) {
                        const long row = Arow0 + wr + ti * 32 + (r & 3) + 8 * (r >> 2) + 4 * l5;
                        const long col = Brow0 + wc + tj * 32 + l31;
                        C[row * ldc + col] = f2bf(acc[ti][tj][r]);
                    }
        }
    } else {
        float* C = (float*)Cvoid;
#pragma unroll
        for (int ti = 0; ti < 2; ++ti)
#pragma unroll
            for (int tj = 0; tj < 2; ++tj)
#pragma unroll
                for (int r = 0; r < 16; ++r) {
                    const long row = Arow0 + wr + ti * 32 + (r & 3) + 8 * (r >> 2) + 4 * l5;
                    const long col = Brow0 + wc + tj * 32 + l31;
                    C[row * ldc + col] = acc[ti][tj][r];
                }
    }
}

// ---------------- flash attention, sliding window ----------------
// grid (T/64, N_KV, B), 512 threads = 8 waves.
// wave w: q-head = hkv*4 + (w&3), q-rows = qt*64 + (w>>2)*32 + [0,32).
// Counted-vmcnt 3-buffer pipeline (T3/T4): stage tile t+2 at top of iter t
// (clamped -> uniform 4 loads/thread/iter), s_waitcnt vmcnt(8) (never 0 in
// loop) + raw s_barrier before consume, second s_barrier after PV protects
// buffer reuse. Q-rope fused at Q-load (pairs (s,s+2) of the fragment hold
// (d,d+64) in-thread). Swapped QK^T, lane-local softmax, exp2 domain,
// defer-max, wave-uniform mask hoisting, LDS P roundtrip.

__global__ __launch_bounds__(512, 2)
void attn_kernel(const unsigned short* __restrict__ qkv,
                 const unsigned short* __restrict__ vt,
                 const float* __restrict__ cosT, const float* __restrict__ sinT,
                 unsigned short* __restrict__ aout) {
    const int qt = blockIdx.x, hkv = blockIdx.y, b = blockIdx.z;
    const int tid = threadIdx.x, lane = tid & 63, w = tid >> 6;
    const int qh = hkv * 4 + (w & 3);          // q-head for this wave
    const int qsub = w >> 2;                   // 0 or 1: which 32-row half
    const int q0w = qt * 64 + qsub * 32;       // wave's first q-row
    const int lo = lane & 15, hi = lane >> 4;

    __shared__ __align__(16) unsigned short sK[3][64 * 128];   // [key][d], chunk-swizzled (48 KB)
    __shared__ __align__(16) unsigned short sV[3][128 * 64];   // [d][key], chunk-swizzled (48 KB)
    __shared__ __align__(16) unsigned short plds[8][32 * 64];  // per-wave P (32 KB)
    unsigned short* pl = plds[w];

    // ---- Q load (raw) + in-register RoPE + scale ----
    bf16x8 qf2[2][4];
#pragma unroll
    for (int f = 0; f < 2; ++f) {
        const unsigned short* qp = qkv + (long)(b * T_SEQ + q0w + f * 16 + lo) * NQKV + qh * HD + hi * 8;
#pragma unroll
        for (int s = 0; s < 4; ++s) qf2[f][s] = *(const bf16x8*)(qp + s * 32);
    }
#pragma unroll
    for (int f = 0; f < 2; ++f) {
        const int t = q0w + f * 16 + lo;
        const float* cb = cosT + t * 64 + hi * 8;
        const float* sb = sinT + t * 64 + hi * 8;
        float c0[8], s0[8], c1[8], s1[8];
        *(float4*)&c0[0] = *(const float4*)cb;        *(float4*)&c0[4] = *(const float4*)(cb + 4);
        *(float4*)&c1[0] = *(const float4*)(cb + 32); *(float4*)&c1[4] = *(const float4*)(cb + 36);
        *(float4*)&s0[0] = *(const float4*)sb;        *(float4*)&s0[4] = *(const float4*)(sb + 4);
        *(float4*)&s1[0] = *(const float4*)(sb + 32); *(float4*)&s1[4] = *(const float4*)(sb + 36);
#pragma unroll
        for (int j = 0; j < 8; ++j) {
            const float a0 = bf2f(qf2[f][0][j]), a1 = bf2f(qf2[f][1][j]);
            const float a2 = bf2f(qf2[f][2][j]), a3 = bf2f(qf2[f][3][j]);
            qf2[f][0][j] = f2bf((a0 * c0[j] - a2 * s0[j]) * QK_SCALE_L2E);
            qf2[f][2][j] = f2bf((a2 * c0[j] + a0 * s0[j]) * QK_SCALE_L2E);
            qf2[f][1][j] = f2bf((a1 * c1[j] - a3 * s1[j]) * QK_SCALE_L2E);
            qf2[f][3][j] = f2bf((a3 * c1[j] + a1 * s1[j]) * QK_SCALE_L2E);
        }
    }

    f32x4 of[8][2] = {};
    float m_r[2] = { -1e30f, -1e30f };   // running max for q = q0w + f*16 + lo
    float s_r[2] = { 0.f, 0.f };

    int kstart = qt * 64 - (WIN - 1);
    if (kstart < 0) kstart = 0;
    kstart &= ~63;
    const int kend = qt * 64 + 63;
    const int ktmax = T_SEQ - 64;

    const unsigned short* kbase = qkv + (long)b * T_SEQ * NQKV + DM + hkv * HD;
    const unsigned short* vbase = vt + (long)(b * N_KV + hkv) * HD * T_SEQ;

    // staging offsets (pre-swizzled global source, linear LDS dest); 512 thr x 2 chunks each
    int kr[2], kc[2], vr[2], vc[2];
#pragma unroll
    for (int u = 0; u < 2; ++u) {
        const int c = u * 512 + tid;
        kr[u] = c >> 4;  kc[u] = (c & 15) ^ (kr[u] & 7);   // sK: 16 chunks/row
        vr[u] = c >> 3;  vc[u] = (c & 7) ^ (vr[u] & 7);    // sV: 8 chunks/row
    }

#define STAGE(bf, kt_) do {                                                              \
    _Pragma("unroll")                                                                    \
    for (int u = 0; u < 2; ++u) {                                                        \
        const int dbase = (u * 512 + w * 64) * 8;                                        \
        GLOAD_LDS16(kbase + (long)((kt_) + kr[u]) * NQKV + kc[u] * 8, &sK[bf][dbase]);   \
        GLOAD_LDS16(vbase + (long)vr[u] * T_SEQ + (kt_) + vc[u] * 8, &sV[bf][dbase]);    \
    } } while (0)

    STAGE(0, kstart);
    {
        int k1 = kstart + 64; if (k1 > ktmax) k1 = ktmax;
        STAGE(1, k1);
    }

    int bufc = 0;
    for (int kt = kstart; kt <= kend; kt += 64) {
        // stage tile t+2 (clamped: always 4 loads/thread -> uniform vmcnt)
        int kt2 = kt + 128; if (kt2 > ktmax) kt2 = ktmax;
        const int bs = (bufc + 2 >= 3) ? bufc - 1 : bufc + 2;
        STAGE(bs, kt2);
        asm volatile("s_waitcnt vmcnt(8)" ::: "memory");   // tile t complete; t+1,t+2 in flight
        __builtin_amdgcn_s_barrier();

        // ---- swapped QK^T: sf[n][f] = S^T[key = kt+n*16+hi*4+r][q = q0w+f*16+lo] ----
        f32x4 sf[4][2] = {};
        __builtin_amdgcn_s_setprio(1);
#pragma unroll
        for (int n = 0; n < 4; ++n) {
            const int row = n * 16 + lo;
#pragma unroll
            for (int s = 0; s < 4; ++s) {
                const int c = (s * 4 + hi) ^ (row & 7);
                bf16x8 kf = *(const bf16x8*)&sK[bufc][row * 128 + c * 8];
                sf[n][0] = __builtin_amdgcn_mfma_f32_16x16x32_bf16(kf, qf2[0][s], sf[n][0], 0, 0, 0);
                sf[n][1] = __builtin_amdgcn_mfma_f32_16x16x32_bf16(kf, qf2[1][s], sf[n][1], 0, 0, 0);
            }
        }
        __builtin_amdgcn_s_setprio(0);

        // ---- wave-uniform mask hoisting: interior tiles skip all masking ----
        const bool nomask = ((kt + 63) <= q0w) && ((q0w + 31 - kt) < WIN);

        // ---- lane-local online softmax, 2 q-frags ----
        float pv[2][4][4];
        float mx[2] = { -1e30f, -1e30f };
        if (nomask) {
#pragma unroll
            for (int f = 0; f < 2; ++f)
#pragma unroll
                for (int n = 0; n < 4; ++n)
#pragma unroll
                    for (int r = 0; r < 4; ++r) {
                        pv[f][n][r] = sf[n][f][r];
                        mx[f] = fmaxf(mx[f], pv[f][n][r]);
                    }
        } else {
#pragma unroll
            for (int f = 0; f < 2; ++f) {
                const int q = q0w + f * 16 + lo;
#pragma unroll
                for (int n = 0; n < 4; ++n)
#pragma unroll
                    for (int r = 0; r < 4; ++r) {
                        const int d = q - (kt + n * 16 + hi * 4 + r);
                        pv[f][n][r] = (d >= 0 && d < WIN) ? sf[n][f][r] : -1e30f;
                        mx[f] = fmaxf(mx[f], pv[f][n][r]);
                    }
            }
        }
#pragma unroll
        for (int f = 0; f < 2; ++f) {
            mx[f] = fmaxf(mx[f], __shfl_xor(mx[f], 16));
            mx[f] = fmaxf(mx[f], __shfl_xor(mx[f], 32));
        }

        const bool ok = (mx[0] <= m_r[0] + 8.0f) && (mx[1] <= m_r[1] + 8.0f);
        if (!__all(ok)) {                          // defer-max: rescale rarely
#pragma unroll
            for (int f = 0; f < 2; ++f) {
                const float mnew = fmaxf(m_r[f], mx[f]);
                const float resc = exp2f(m_r[f] - mnew);
                s_r[f] *= resc;
                m_r[f] = mnew;
                float r4[4];
#pragma unroll
                for (int r = 0; r < 4; ++r) r4[r] = __shfl(resc, hi * 4 + r);
#pragma unroll
                for (int j = 0; j < 8; ++j) {
                    of[j][f][0] *= r4[0]; of[j][f][1] *= r4[1];
                    of[j][f][2] *= r4[2]; of[j][f][3] *= r4[3];
                }
            }
        }

#pragma unroll
        for (int f = 0; f < 2; ++f) {
            float psum = 0.f;
#pragma unroll
            for (int n = 0; n < 4; ++n)
#pragma unroll
                for (int r = 0; r < 4; ++r) {
                    pv[f][n][r] = exp2f(pv[f][n][r] - m_r[f]);
                    psum += pv[f][n][r];
                }
            psum += __shfl_xor(psum, 16);
            psum += __shfl_xor(psum, 32);
            s_r[f] += psum;
        }

        // ---- pack P -> per-wave swizzled LDS (u32 writes, cvt_pk) ----
        const int swz = (lo & 7) << 3;
#pragma unroll
        for (int f = 0; f < 2; ++f) {
            const int rowq = f * 16 + lo;
#pragma unroll
            for (int n = 0; n < 4; ++n) {
                const int k0 = n * 16 + hi * 4;
                *(unsigned*)&pl[rowq * 64 + (k0 ^ swz)]       = cvt_pk_bf16(pv[f][n][0], pv[f][n][1]);
                *(unsigned*)&pl[rowq * 64 + ((k0 + 2) ^ swz)] = cvt_pk_bf16(pv[f][n][2], pv[f][n][3]);
            }
        }
        asm volatile("s_waitcnt lgkmcnt(0)" ::: "memory");
        __builtin_amdgcn_sched_barrier(0);
        bf16x8 pa2[2][2];
#pragma unroll
        for (int f = 0; f < 2; ++f)
#pragma unroll
            for (int ks = 0; ks < 2; ++ks) {
                const int c = (ks * 4 + hi) ^ (lo & 7);
                pa2[f][ks] = *(const bf16x8*)&pl[(f * 16 + lo) * 64 + c * 8];
            }

        // ---- PV: of[j][f] += P[q-frag f] . V[d=j*16+lo] ----
        __builtin_amdgcn_s_setprio(1);
#pragma unroll
        for (int j = 0; j < 8; ++j) {
            const int row = j * 16 + lo;
#pragma unroll
            for (int ks = 0; ks < 2; ++ks) {
                const int c = (ks * 4 + hi) ^ (row & 7);
                bf16x8 vf = *(const bf16x8*)&sV[bufc][row * 64 + c * 8];
                of[j][0] = __builtin_amdgcn_mfma_f32_16x16x32_bf16(pa2[0][ks], vf, of[j][0], 0, 0, 0);
                of[j][1] = __builtin_amdgcn_mfma_f32_16x16x32_bf16(pa2[1][ks], vf, of[j][1], 0, 0, 0);
            }
        }
        __builtin_amdgcn_s_setprio(0);

        __builtin_amdgcn_s_barrier();      // reads of buf t done before iter t+1 rewrites it
        bufc = (bufc + 1 >= 3) ? 0 : bufc + 1;
    }
#undef STAGE

#pragma unroll
    for (int f = 0; f < 2; ++f) {
        float s4[4];
#pragma unroll
        for (int r = 0; r < 4; ++r) s4[r] = __shfl(s_r[f], hi * 4 + r);
#pragma unroll
        for (int r = 0; r < 4; ++r) {
            const int qrow = q0w + f * 16 + hi * 4 + r;
            const float inv = 1.0f / s4[r];
            unsigned short* op = aout + (long)(b * T_SEQ + qrow) * DM + qh * HD + lo;
#pragma unroll
            for (int j = 0; j < 8; ++j) op[j * 16] = f2bf(of[j][f][r] * inv);
        }
    }
}

// ---------------- launch ----------------

extern "C" void kernel_launch(void* const* d_in, const int* in_sizes, int n_in,
                              void* d_out, int out_size, void* d_ws, size_t ws_size,
                              hipStream_t stream) {
    (void)in_sizes; (void)n_in; (void)out_size; (void)ws_size;
    const float* x  = (const float*)d_in[0];
    const float* wq = (const float*)d_in[1];
    const float* wk = (const float*)d_in[2];
    const float* wv = (const float*)d_in[3];
    const float* wo = (const float*)d_in[4];
    float* out = (float*)d_out;
    char* ws = (char*)d_ws;

    unsigned short* xbf   = (unsigned short*)(ws);                // 16,777,216 B
    unsigned short* wqkvT = (unsigned short*)(ws + 16777216);     // 12,582,912 B
    unsigned short* woT   = (unsigned short*)(ws + 29360128);     //  8,388,608 B
    unsigned short* qkv   = (unsigned short*)(ws + 37748736);     // 25,165,824 B
    unsigned short* vt    = (unsigned short*)(ws + 62914560);     //  4,194,304 B
    unsigned short* aout  = (unsigned short*)(ws + 67108864);     // 16,777,216 B
    float* cosT = (float*)(ws + 83886080);                        //    524,288 B
    float* sinT = (float*)(ws + 84410368);                        //    524,288 B

    prep_a<<<dim3(18944), dim3(256), 0, stream>>>(x, wq, wk, wv, wo, xbf, wqkvT, woT, cosT, sinT);
    gemm_bt<1><<<dim3(NQKV / 128, 32), dim3(256), 0, stream>>>(xbf, wqkvT, qkv, DM, NQKV, vt);
    prep_b<<<dim3(1024), dim3(256), 0, stream>>>(qkv, cosT, sinT);
    attn_kernel<<<dim3(T_SEQ / 64, 4, 2), dim3(512), 0, stream>>>(qkv, vt, cosT, sinT, aout);
    gemm_bt<0><<<dim3(DM / 128, 32), dim3(256), 0, stream>>>(aout, woT, out, DM, DM, nullptr);
}

// Round 16
// 162.757 us; speedup vs baseline: 1.0803x; 1.0002x over previous
//
#include <hip/hip_runtime.h>

#define T_SEQ   2048
#define DM      2048
#define N_Q     16
#define N_KV    4
#define HD      128
#define WIN     512
#define NB      2
#define NQKV    3072
// 1/sqrt(128) * log2(e): attention computed in exp2 domain
#define QK_SCALE_L2E 0.12751744f

typedef short bf16x8 __attribute__((ext_vector_type(8)));
typedef float f32x4  __attribute__((ext_vector_type(4)));
typedef float f32x16 __attribute__((ext_vector_type(16)));
typedef unsigned short us4v __attribute__((ext_vector_type(4)));

__device__ __forceinline__ unsigned short f2bf(float f) {
    union { float f; unsigned u; } v; v.f = f;
    unsigned u = v.u;
    u += 0x7fffu + ((u >> 16) & 1u);           // RNE
    return (unsigned short)(u >> 16);
}
__device__ __forceinline__ float bf2f(unsigned short h) {
    union { unsigned u; float f; } v; v.u = ((unsigned)h) << 16;
    return v.f;
}
__device__ __forceinline__ unsigned cvt_pk_bf16(float a, float b) {
    unsigned r;
    asm("v_cvt_pk_bf16_f32 %0, %1, %2" : "=v"(r) : "v"(a), "v"(b));
    return r;   // low16 = bf16(a), high16 = bf16(b)
}

#define GLOAD_LDS16(g, l) __builtin_amdgcn_global_load_lds( \
    (const __attribute__((address_space(1))) void*)(g),     \
    (__attribute__((address_space(3))) void*)(l), 16, 0, 0)

struct us4 { unsigned short a, b, c, d; };

// ---------------- fused prep A: x->bf16, 4 weight transposes (64x64 tiles,
// full-128B-line writes), rope table ----------------
// flat grid: [0,8192) x-convert | [8192,10752) transposes | [10752,11264) rope

__global__ __launch_bounds__(256)
void prep_a(const float* __restrict__ x, const float* __restrict__ wq,
            const float* __restrict__ wk, const float* __restrict__ wv,
            const float* __restrict__ wo,
            unsigned short* __restrict__ xbf, unsigned short* __restrict__ wqkvT,
            unsigned short* __restrict__ woT,
            float* __restrict__ cosT, float* __restrict__ sinT) {
    __shared__ float tile[64][65];
    int blk = blockIdx.x;
    if (blk < 8192) {                               // x: f32 -> bf16, 4 elems/thread
        long i = ((long)blk * 256 + threadIdx.x) * 4;
        float4 f = *(const float4*)(x + i);
        us4 o; o.a = f2bf(f.x); o.b = f2bf(f.y); o.c = f2bf(f.z); o.d = f2bf(f.w);
        *(us4*)(xbf + i) = o;
        return;
    }
    blk -= 8192;
    if (blk < 2560) {                               // weight transposes, 64x64
        const float* in; unsigned short* outp; int C, bx, by;
        if (blk < 1024)      { in = wq; outp = wqkvT;                          C = DM;  bx = blk & 31;  by = blk >> 5; }
        else if (blk < 1280) { int k = blk - 1024; in = wk; outp = wqkvT + (long)DM * DM;         C = 512; bx = k & 7; by = k >> 3; }
        else if (blk < 1536) { int k = blk - 1280; in = wv; outp = wqkvT + (long)(DM + 512) * DM; C = 512; bx = k & 7; by = k >> 3; }
        else                 { int k = blk - 1536; in = wo; outp = woT;                           C = DM;  bx = k & 31; by = k >> 5; }
        const int c0 = bx * 64, r0 = by * 64;
        const int tx = threadIdx.x & 63, ty = threadIdx.x >> 6;
#pragma unroll
        for (int i = 0; i < 16; ++i)
            tile[ty + i * 4][tx] = in[(long)(r0 + ty + i * 4) * C + c0 + tx];
        __syncthreads();
#pragma unroll
        for (int i = 0; i < 16; ++i)
            outp[(long)(c0 + ty + i * 4) * DM + r0 + tx] = f2bf(tile[tx][ty + i * 4]);
        return;
    }
    blk -= 2560;                                    // rope table (512 blocks)
    const int idx = blk * 256 + threadIdx.x;        // < 2048*64
    const int t = idx >> 6, d = idx & 63;
    const float inv = __expf(-(float)d * (9.210340371976184f / 64.0f)); // 10000^(-d/64)
    const float ang = (float)t * inv;
    cosT[idx] = cosf(ang);
    sinT[idx] = sinf(ang);
}

// ---------------- prep B: rope apply on K only (q-rope fused into attn,
// v written transposed by the qkv GEMM epilogue). 1024 blocks.

__global__ __launch_bounds__(256)
void prep_b(unsigned short* __restrict__ qkv,
            const float* __restrict__ cosT, const float* __restrict__ sinT) {
    const int idx = blockIdx.x * 256 + threadIdx.x;    // 4096 rows * 4 kheads * 16
    const int d4 = (idx & 15) * 4;
    const int hh = (idx >> 4) & 3;
    const int row = idx >> 6;
    const int t = row & (T_SEQ - 1);
    const int col = DM + hh * HD + d4;
    unsigned short* p = qkv + (long)row * NQKV + col;
    us4v a = *(const us4v*)p;
    us4v b = *(const us4v*)(p + 64);
    float4 c = *(const float4*)&cosT[t * 64 + d4];
    float4 s = *(const float4*)&sinT[t * 64 + d4];
    us4v o1, o2;
    const float cc[4] = { c.x, c.y, c.z, c.w }, ss[4] = { s.x, s.y, s.z, s.w };
#pragma unroll
    for (int i = 0; i < 4; ++i) {
        const float av = bf2f(a[i]), bv = bf2f(b[i]);
        o1[i] = f2bf(av * cc[i] - bv * ss[i]);
        o2[i] = f2bf(bv * cc[i] + av * ss[i]);
    }
    *(us4v*)p        = o1;
    *(us4v*)(p + 64) = o2;
}

// ---------------- GEMM: C[M][ldc] = A[M][K] * Bt[N][K]^T ----------------
// m97 structure, 32x32x16 MFMA. For OUT_BF16 (qkv projection): v col-blocks
// (hb>=20, block-uniform) write DIRECTLY to vt[b][hkv][d][t] (transposed).
// C/D map (HW-verified m74/m101): col=lane&31, row=(r&3)+8*(r>>2)+4*(lane>>5).

template<int OUT_BF16>
__global__ __launch_bounds__(256)
void gemm_bt(const unsigned short* __restrict__ A,
             const unsigned short* __restrict__ Bt,
             void* __restrict__ Cvoid, int K, int ldc,
             unsigned short* __restrict__ vt) {
    __shared__ __align__(16) unsigned short sA[128 * 64];
    __shared__ __align__(16) unsigned short sB[128 * 64];
    const int tid = threadIdx.x;
    const int lane = tid & 63;
    const int wid = tid >> 6;
    const int wr = (wid >> 1) * 64, wc = (wid & 1) * 64;
    const int l5 = lane >> 5, l31 = lane & 31;

    // XCD-aware bijective swizzle (nwg divisible by 8 in all launches)
    const int gx = gridDim.x;
    const int nwg = gx * gridDim.y;
    int flat = blockIdx.y * gx + blockIdx.x;
    flat = (flat & 7) * (nwg >> 3) + (flat >> 3);
    const long Arow0 = (long)(flat / gx) * 128;
    const long Brow0 = (long)(flat % gx) * 128;

    f32x16 acc[2][2] = {};

    for (int kt = 0; kt < K; kt += 64) {
        __syncthreads();
#pragma unroll
        for (int n = 0; n < 4; ++n) {
            const int linb = n * 256 + wid * 64;      // wave-uniform 16B-chunk base
            const int lin  = linb + lane;             // this lane's chunk
            const int row  = lin >> 3;                // 8 chunks per 64-elem row
            const int sw   = (row ^ (row >> 3)) & 7;
            const int sc   = (lin & 7) ^ sw;          // pre-swizzled global source
            const unsigned short* gA = A  + (Arow0 + row) * K + kt + sc * 8;
            const unsigned short* gB = Bt + (Brow0 + row) * K + kt + sc * 8;
            GLOAD_LDS16(gA, &sA[linb * 8]);
            GLOAD_LDS16(gB, &sB[linb * 8]);
        }
        __syncthreads();
#pragma unroll
        for (int kc = 0; kc < 4; ++kc) {
            bf16x8 av[2], bv[2];
#pragma unroll
            for (int t = 0; t < 2; ++t) {
                const int rowa = wr + t * 32 + l31;
                const int ca = (kc * 2 + l5) ^ ((rowa ^ (rowa >> 3)) & 7);
                av[t] = *(const bf16x8*)&sA[rowa * 64 + ca * 8];
                const int rowb = wc + t * 32 + l31;
                const int cb = (kc * 2 + l5) ^ ((rowb ^ (rowb >> 3)) & 7);
                bv[t] = *(const bf16x8*)&sB[rowb * 64 + cb * 8];
            }
#pragma unroll
            for (int ti = 0; ti < 2; ++ti)
#pragma unroll
                for (int tj = 0; tj < 2; ++tj)
                    acc[ti][tj] = __builtin_amdgcn_mfma_f32_32x32x16_bf16(av[ti], bv[tj], acc[ti][tj], 0, 0, 0);
        }
    }

    if (OUT_BF16) {
        const int hb = (int)(Brow0 >> 7);            // 0-15 q, 16-19 k, 20-23 v
        unsigned short* C = (unsigned short*)Cvoid;
        if (hb >= 20) {
            // v: write transposed into vt[(b*4+hkv)*128 + d][t]
            const long bb = Arow0 >> 11;             // batch (uniform per block)
            const int hkv = hb - 20;
#pragma unroll
            for (int ti = 0; ti < 2; ++ti)
#pragma unroll
                for (int tj = 0; tj < 2; ++tj) {
                    const int d = wc + tj * 32 + l31;
                    unsigned short* vp = vt + ((bb * 4 + hkv) * 128 + d) * (long)T_SEQ;
#pragma unroll
                    for (int r = 0; r < 16; ++r) {
                        const int t = (int)((Arow0 + wr + ti * 32 + (r & 3) + 8 * (r >> 2) + 4 * l5) & (T_SEQ - 1));
                        vp[t] = f2bf(acc[ti][tj][r]);
                    }
                }
        } else {
#pragma unroll
            for (int ti = 0; ti < 2; ++ti)
#pragma unroll
                for (int tj = 0; tj < 2; ++tj)
#pragma unroll
                    for (int r = 0; r < 16; ++r) {
                        const long row = Arow0 + wr + ti * 32 + (r & 3) + 8 * (r >> 2) + 4 * l5;
                        const long col = Brow0 + wc + tj * 32 + l31;
                        C[row * ldc + col] = f2bf(acc[ti][tj][r]);
                    }
        }
    } else {
        float* C = (float*)Cvoid;
#pragma unroll
        for (int ti = 0; ti < 2; ++ti)
#pragma unroll
            for (int tj = 0; tj < 2; ++tj)
#pragma unroll
                for (int r = 0; r < 16; ++r) {
                    const long row = Arow0 + wr + ti * 32 + (r & 3) + 8 * (r >> 2) + 4 * l5;
                    const long col = Brow0 + wc + tj * 32 + l31;
                    C[row * ldc + col] = acc[ti][tj][r];
                }
    }
}

// ---------------- flash attention, sliding window ----------------
// grid (T/64, N_KV, B), 512 threads = 8 waves.
// wave w: q-head = hkv*4 + (w&3), q-rows = qt*64 + (w>>2)*32 + [0,32).
// Counted-vmcnt 3-buffer pipeline (T3/T4), Q-rope fused at Q-load, swapped
// QK^T, lane-local softmax, exp2 domain, defer-max, wave-uniform mask
// hoisting, LDS P roundtrip.

__global__ __launch_bounds__(512, 2)
void attn_kernel(const unsigned short* __restrict__ qkv,
                 const unsigned short* __restrict__ vt,
                 const float* __restrict__ cosT, const float* __restrict__ sinT,
                 unsigned short* __restrict__ aout) {
    const int qt = blockIdx.x, hkv = blockIdx.y, b = blockIdx.z;
    const int tid = threadIdx.x, lane = tid & 63, w = tid >> 6;
    const int qh = hkv * 4 + (w & 3);          // q-head for this wave
    const int qsub = w >> 2;                   // 0 or 1: which 32-row half
    const int q0w = qt * 64 + qsub * 32;       // wave's first q-row
    const int lo = lane & 15, hi = lane >> 4;

    __shared__ __align__(16) unsigned short sK[3][64 * 128];   // [key][d], chunk-swizzled (48 KB)
    __shared__ __align__(16) unsigned short sV[3][128 * 64];   // [d][key], chunk-swizzled (48 KB)
    __shared__ __align__(16) unsigned short plds[8][32 * 64];  // per-wave P (32 KB)
    unsigned short* pl = plds[w];

    // ---- Q load (raw) + in-register RoPE + scale ----
    bf16x8 qf2[2][4];
#pragma unroll
    for (int f = 0; f < 2; ++f) {
        const unsigned short* qp = qkv + (long)(b * T_SEQ + q0w + f * 16 + lo) * NQKV + qh * HD + hi * 8;
#pragma unroll
        for (int s = 0; s < 4; ++s) qf2[f][s] = *(const bf16x8*)(qp + s * 32);
    }
#pragma unroll
    for (int f = 0; f < 2; ++f) {
        const int t = q0w + f * 16 + lo;
        const float* cb = cosT + t * 64 + hi * 8;
        const float* sb = sinT + t * 64 + hi * 8;
        float c0[8], s0[8], c1[8], s1[8];
        *(float4*)&c0[0] = *(const float4*)cb;        *(float4*)&c0[4] = *(const float4*)(cb + 4);
        *(float4*)&c1[0] = *(const float4*)(cb + 32); *(float4*)&c1[4] = *(const float4*)(cb + 36);
        *(float4*)&s0[0] = *(const float4*)sb;        *(float4*)&s0[4] = *(const float4*)(sb + 4);
        *(float4*)&s1[0] = *(const float4*)(sb + 32); *(float4*)&s1[4] = *(const float4*)(sb + 36);
#pragma unroll
        for (int j = 0; j < 8; ++j) {
            const float a0 = bf2f(qf2[f][0][j]), a1 = bf2f(qf2[f][1][j]);
            const float a2 = bf2f(qf2[f][2][j]), a3 = bf2f(qf2[f][3][j]);
            qf2[f][0][j] = f2bf((a0 * c0[j] - a2 * s0[j]) * QK_SCALE_L2E);
            qf2[f][2][j] = f2bf((a2 * c0[j] + a0 * s0[j]) * QK_SCALE_L2E);
            qf2[f][1][j] = f2bf((a1 * c1[j] - a3 * s1[j]) * QK_SCALE_L2E);
            qf2[f][3][j] = f2bf((a3 * c1[j] + a1 * s1[j]) * QK_SCALE_L2E);
        }
    }

    f32x4 of[8][2] = {};
    float m_r[2] = { -1e30f, -1e30f };   // running max for q = q0w + f*16 + lo
    float s_r[2] = { 0.f, 0.f };

    int kstart = qt * 64 - (WIN - 1);
    if (kstart < 0) kstart = 0;
    kstart &= ~63;
    const int kend = qt * 64 + 63;
    const int ktmax = T_SEQ - 64;

    const unsigned short* kbase = qkv + (long)b * T_SEQ * NQKV + DM + hkv * HD;
    const unsigned short* vbase = vt + (long)(b * N_KV + hkv) * HD * T_SEQ;

    // staging offsets (pre-swizzled global source, linear LDS dest); 512 thr x 2 chunks each
    int kr[2], kc[2], vr[2], vc[2];
#pragma unroll
    for (int u = 0; u < 2; ++u) {
        const int c = u * 512 + tid;
        kr[u] = c >> 4;  kc[u] = (c & 15) ^ (kr[u] & 7);   // sK: 16 chunks/row
        vr[u] = c >> 3;  vc[u] = (c & 7) ^ (vr[u] & 7);    // sV: 8 chunks/row
    }

#define STAGE(bf, kt_) do {                                                              \
    _Pragma("unroll")                                                                    \
    for (int u = 0; u < 2; ++u) {                                                        \
        const int dbase = (u * 512 + w * 64) * 8;                                        \
        GLOAD_LDS16(kbase + (long)((kt_) + kr[u]) * NQKV + kc[u] * 8, &sK[bf][dbase]);   \
        GLOAD_LDS16(vbase + (long)vr[u] * T_SEQ + (kt_) + vc[u] * 8, &sV[bf][dbase]);    \
    } } while (0)

    STAGE(0, kstart);
    {
        int k1 = kstart + 64; if (k1 > ktmax) k1 = ktmax;
        STAGE(1, k1);
    }

    int bufc = 0;
    for (int kt = kstart; kt <= kend; kt += 64) {
        // stage tile t+2 (clamped: always 4 loads/thread -> uniform vmcnt)
        int kt2 = kt + 128; if (kt2 > ktmax) kt2 = ktmax;
        const int bs = (bufc + 2 >= 3) ? bufc - 1 : bufc + 2;
        STAGE(bs, kt2);
        asm volatile("s_waitcnt vmcnt(8)" ::: "memory");   // tile t complete; t+1,t+2 in flight
        __builtin_amdgcn_s_barrier();

        // ---- swapped QK^T: sf[n][f] = S^T[key = kt+n*16+hi*4+r][q = q0w+f*16+lo] ----
        f32x4 sf[4][2] = {};
        __builtin_amdgcn_s_setprio(1);
#pragma unroll
        for (int n = 0; n < 4; ++n) {
            const int row = n * 16 + lo;
#pragma unroll
            for (int s = 0; s < 4; ++s) {
                const int c = (s * 4 + hi) ^ (row & 7);
                bf16x8 kf = *(const bf16x8*)&sK[bufc][row * 128 + c * 8];
                sf[n][0] = __builtin_amdgcn_mfma_f32_16x16x32_bf16(kf, qf2[0][s], sf[n][0], 0, 0, 0);
                sf[n][1] = __builtin_amdgcn_mfma_f32_16x16x32_bf16(kf, qf2[1][s], sf[n][1], 0, 0, 0);
            }
        }
        __builtin_amdgcn_s_setprio(0);

        // ---- wave-uniform mask hoisting: interior tiles skip all masking ----
        const bool nomask = ((kt + 63) <= q0w) && ((q0w + 31 - kt) < WIN);

        // ---- lane-local online softmax, 2 q-frags ----
        float pv[2][4][4];
        float mx[2] = { -1e30f, -1e30f };
        if (nomask) {
#pragma unroll
            for (int f = 0; f < 2; ++f)
#pragma unroll
                for (int n = 0; n < 4; ++n)
#pragma unroll
                    for (int r = 0; r < 4; ++r) {
                        pv[f][n][r] = sf[n][f][r];
                        mx[f] = fmaxf(mx[f], pv[f][n][r]);
                    }
        } else {
#pragma unroll
            for (int f = 0; f < 2; ++f) {
                const int q = q0w + f * 16 + lo;
#pragma unroll
                for (int n = 0; n < 4; ++n)
#pragma unroll
                    for (int r = 0; r < 4; ++r) {
                        const int d = q - (kt + n * 16 + hi * 4 + r);
                        pv[f][n][r] = (d >= 0 && d < WIN) ? sf[n][f][r] : -1e30f;
                        mx[f] = fmaxf(mx[f], pv[f][n][r]);
                    }
            }
        }
#pragma unroll
        for (int f = 0; f < 2; ++f) {
            mx[f] = fmaxf(mx[f], __shfl_xor(mx[f], 16));
            mx[f] = fmaxf(mx[f], __shfl_xor(mx[f], 32));
        }

        const bool ok = (mx[0] <= m_r[0] + 8.0f) && (mx[1] <= m_r[1] + 8.0f);
        if (!__all(ok)) {                          // defer-max: rescale rarely
#pragma unroll
            for (int f = 0; f < 2; ++f) {
                const float mnew = fmaxf(m_r[f], mx[f]);
                const float resc = exp2f(m_r[f] - mnew);
                s_r[f] *= resc;
                m_r[f] = mnew;
                float r4[4];
#pragma unroll
                for (int r = 0; r < 4; ++r) r4[r] = __shfl(resc, hi * 4 + r);
#pragma unroll
                for (int j = 0; j < 8; ++j) {
                    of[j][f][0] *= r4[0]; of[j][f][1] *= r4[1];
                    of[j][f][2] *= r4[2]; of[j][f][3] *= r4[3];
                }
            }
        }

#pragma unroll
        for (int f = 0; f < 2; ++f) {
            float psum = 0.f;
#pragma unroll
            for (int n = 0; n < 4; ++n)
#pragma unroll
                for (int r = 0; r < 4; ++r) {
                    pv[f][n][r] = exp2f(pv[f][n][r] - m_r[f]);
                    psum += pv[f][n][r];
                }
            psum += __shfl_xor(psum, 16);
            psum += __shfl_xor(psum, 32);
            s_r[f] += psum;
        }

        // ---- pack P -> per-wave swizzled LDS (u32 writes, cvt_pk) ----
        const int swz = (lo & 7) << 3;
#pragma unroll
        for (int f = 0; f < 2; ++f) {
            const int rowq = f * 16 + lo;
#pragma unroll
            for (int n = 0; n < 4; ++n) {
                const int k0 = n * 16 + hi * 4;
                *(unsigned*)&pl[rowq * 64 + (k0 ^ swz)]       = cvt_pk_bf16(pv[f][n][0], pv[f][n][1]);
                *(unsigned*)&pl[rowq * 64 + ((k0 + 2) ^ swz)] = cvt_pk_bf16(pv[f][n][2], pv[f][n][3]);
            }
        }
        asm volatile("s_waitcnt lgkmcnt(0)" ::: "memory");
        __builtin_amdgcn_sched_barrier(0);
        bf16x8 pa2[2][2];
#pragma unroll
        for (int f = 0; f < 2; ++f)
#pragma unroll
            for (int ks = 0; ks < 2; ++ks) {
                const int c = (ks * 4 + hi) ^ (lo & 7);
                pa2[f][ks] = *(const bf16x8*)&pl[(f * 16 + lo) * 64 + c * 8];
            }

        // ---- PV: of[j][f] += P[q-frag f] . V[d=j*16+lo] ----
        __builtin_amdgcn_s_setprio(1);
#pragma unroll
        for (int j = 0; j < 8; ++j) {
            const int row = j * 16 + lo;
#pragma unroll
            for (int ks = 0; ks < 2; ++ks) {
                const int c = (ks * 4 + hi) ^ (row & 7);
                bf16x8 vf = *(const bf16x8*)&sV[bufc][row * 64 + c * 8];
                of[j][0] = __builtin_amdgcn_mfma_f32_16x16x32_bf16(pa2[0][ks], vf, of[j][0], 0, 0, 0);
                of[j][1] = __builtin_amdgcn_mfma_f32_16x16x32_bf16(pa2[1][ks], vf, of[j][1], 0, 0, 0);
            }
        }
        __builtin_amdgcn_s_setprio(0);

        __builtin_amdgcn_s_barrier();      // reads of buf t done before iter t+1 rewrites it
        bufc = (bufc + 1 >= 3) ? 0 : bufc + 1;
    }
#undef STAGE

#pragma unroll
    for (int f = 0; f < 2; ++f) {
        float s4[4];
#pragma unroll
        for (int r = 0; r < 4; ++r) s4[r] = __shfl(s_r[f], hi * 4 + r);
#pragma unroll
        for (int r = 0; r < 4; ++r) {
            const int qrow = q0w + f * 16 + hi * 4 + r;
            const float inv = 1.0f / s4[r];
            unsigned short* op = aout + (long)(b * T_SEQ + qrow) * DM + qh * HD + lo;
#pragma unroll
            for (int j = 0; j < 8; ++j) op[j * 16] = f2bf(of[j][f][r] * inv);
        }
    }
}

// ---------------- launch ----------------

extern "C" void kernel_launch(void* const* d_in, const int* in_sizes, int n_in,
                              void* d_out, int out_size, void* d_ws, size_t ws_size,
                              hipStream_t stream) {
    (void)in_sizes; (void)n_in; (void)out_size; (void)ws_size;
    const float* x  = (const float*)d_in[0];
    const float* wq = (const float*)d_in[1];
    const float* wk = (const float*)d_in[2];
    const float* wv = (const float*)d_in[3];
    const float* wo = (const float*)d_in[4];
    float* out = (float*)d_out;
    char* ws = (char*)d_ws;

    unsigned short* xbf   = (unsigned short*)(ws);                // 16,777,216 B
    unsigned short* wqkvT = (unsigned short*)(ws + 16777216);     // 12,582,912 B
    unsigned short* woT   = (unsigned short*)(ws + 29360128);     //  8,388,608 B
    unsigned short* qkv   = (unsigned short*)(ws + 37748736);     // 25,165,824 B
    unsigned short* vt    = (unsigned short*)(ws + 62914560);     //  4,194,304 B
    unsigned short* aout  = (unsigned short*)(ws + 67108864);     // 16,777,216 B
    float* cosT = (float*)(ws + 83886080);                        //    524,288 B
    float* sinT = (float*)(ws + 84410368);                        //    524,288 B

    prep_a<<<dim3(11264), dim3(256), 0, stream>>>(x, wq, wk, wv, wo, xbf, wqkvT, woT, cosT, sinT);
    gemm_bt<1><<<dim3(NQKV / 128, 32), dim3(256), 0, stream>>>(xbf, wqkvT, qkv, DM, NQKV, vt);
    prep_b<<<dim3(1024), dim3(256), 0, stream>>>(qkv, cosT, sinT);
    attn_kernel<<<dim3(T_SEQ / 64, 4, 2), dim3(512), 0, stream>>>(qkv, vt, cosT, sinT, aout);
    gemm_bt<0><<<dim3(DM / 128, 32), dim3(256), 0, stream>>>(aout, woT, out, DM, DM, nullptr);
}